// Round 1
// 461.029 us; speedup vs baseline: 1.6537x; 1.6537x over previous
//
#include <hip/hip_runtime.h>
#include <stdint.h>

#define N_B 32
#define C_D 256
#define T_D 1024

typedef unsigned short u16;
typedef __attribute__((ext_vector_type(8))) short short8;
typedef __attribute__((ext_vector_type(4))) float f32x4;

__device__ __forceinline__ u16 f2bf(float f) {
    unsigned x = __float_as_uint(f);
    return (u16)((x + 0x7fffu + ((x >> 16) & 1u)) >> 16);  // RNE
}

__device__ __forceinline__ void gld16(const void* g, void* l) {
    __builtin_amdgcn_global_load_lds(
        (const __attribute__((address_space(1))) uint32_t*)g,
        (__attribute__((address_space(3))) uint32_t*)l, 16, 0, 0);
}

// ------- convert+transpose: X fp32 (n,c,t) -> XT bf16 (n,t,c), 64x64 tiles -------
__global__ __launch_bounds__(256) void ct_f2b(const float* __restrict__ X,
                                              u16* __restrict__ XT) {
    __shared__ u16 lds[64][65];
    const int n  = blockIdx.z;
    const int t0 = blockIdx.x * 64;
    const int c0 = blockIdx.y * 64;
    const float* Xn = X + (size_t)n * (C_D * T_D);
    u16* XTn = XT + (size_t)n * (T_D * C_D);
    const int tid = threadIdx.x;
    const int row = tid >> 2;        // 0..63 (c within tile)
    const int tq  = (tid & 3) * 16;  // t-base within tile
    const float* src = Xn + (size_t)(c0 + row) * T_D + t0 + tq;
#pragma unroll
    for (int i = 0; i < 4; ++i) {
        float4 v = *(const float4*)(src + i * 4);
        lds[row][tq + i * 4 + 0] = f2bf(v.x);
        lds[row][tq + i * 4 + 1] = f2bf(v.y);
        lds[row][tq + i * 4 + 2] = f2bf(v.z);
        lds[row][tq + i * 4 + 3] = f2bf(v.w);
    }
    __syncthreads();
    const int r  = tid >> 3;
    const int c8 = (tid & 7) * 8;
#pragma unroll
    for (int p = 0; p < 2; ++p) {
        const int tt = r + p * 32;  // t within tile
        union { u16 u[8]; uint4 v; } o;
#pragma unroll
        for (int j = 0; j < 8; ++j) o.u[j] = lds[c8 + j][tt];
        *(uint4*)(XTn + (size_t)(t0 + tt) * C_D + c0 + c8) = o.v;
    }
}

// ---------------- convert fp32 -> bf16, flat ----------------
__global__ __launch_bounds__(256) void conv_f2b(const float* __restrict__ in,
                                                u16* __restrict__ out, int n) {
    int i = blockIdx.x * 256 + threadIdx.x;
    if (i < n) out[i] = f2bf(in[i]);
}

// --------- GEMM: Out[m,n] = epi(scale * sum_k A[m,k]*B[n,k] (+bias)) -------
// A,B bf16 (rows K-contig). Out fp32 if F32OUT else bf16.
// EPI: 0 = scale only; 1 = tanh(x + bias[n]); 2 = tanh(x + bias[m])
template <int EPI, bool F32OUT>
__global__ __launch_bounds__(256) void gemm_abt(
        const u16* __restrict__ A, const u16* __restrict__ B,
        const float* __restrict__ bias, void* __restrict__ OutV,
        int Kdim, int ldo, long sA, long sB, long sO, float scale)
{
    __shared__ __align__(16) u16 smA[128 * 32];
    __shared__ __align__(16) u16 smB[128 * 32];

    const int nb = blockIdx.z;
    const int n0 = blockIdx.x * 128;
    const int m0 = blockIdx.y * 128;
    const int tid = threadIdx.x;

    const u16* Ab = A + (size_t)nb * sA;
    const u16* Bb = B + (size_t)nb * sB;

    const int srow = tid >> 2;
    const int sk8  = (tid & 3) * 8;
    const u16* gA0 = Ab + (size_t)(m0 + srow) * Kdim + sk8;
    const u16* gA1 = gA0 + (size_t)64 * Kdim;
    const u16* gB0 = Bb + (size_t)(n0 + srow) * Kdim + sk8;
    const u16* gB1 = gB0 + (size_t)64 * Kdim;
    u16* lA0 = smA + tid * 8;
    u16* lA1 = smA + 2048 + tid * 8;
    u16* lB0 = smB + tid * 8;
    u16* lB1 = smB + 2048 + tid * 8;

    const int lane = tid & 63;
    const int w    = tid >> 6;
    const int wm   = (w >> 1) * 64;
    const int wn   = (w & 1) * 64;
    const int l15  = lane & 15;
    const int quad = lane >> 4;

    f32x4 acc[4][4];
#pragma unroll
    for (int i = 0; i < 4; ++i)
#pragma unroll
        for (int j = 0; j < 4; ++j) acc[i][j] = (f32x4){0.f, 0.f, 0.f, 0.f};

    for (int kb = 0; kb < Kdim; kb += 32) {
        gld16(gA0 + kb, lA0);
        gld16(gA1 + kb, lA1);
        gld16(gB0 + kb, lB0);
        gld16(gB1 + kb, lB1);
        __syncthreads();
        short8 af[4], bfr[4];
#pragma unroll
        for (int i = 0; i < 4; ++i) {
            af[i]  = *(const short8*)(smA + (wm + i * 16 + l15) * 32 + quad * 8);
            bfr[i] = *(const short8*)(smB + (wn + i * 16 + l15) * 32 + quad * 8);
        }
#pragma unroll
        for (int mi = 0; mi < 4; ++mi)
#pragma unroll
            for (int ni = 0; ni < 4; ++ni)
                acc[mi][ni] = __builtin_amdgcn_mfma_f32_16x16x32_bf16(
                        af[mi], bfr[ni], acc[mi][ni], 0, 0, 0);
        __syncthreads();
    }

#pragma unroll
    for (int mi = 0; mi < 4; ++mi) {
        const int mb = m0 + wm + mi * 16 + quad * 4;
#pragma unroll
        for (int r = 0; r < 4; ++r) {
            const int m = mb + r;
            float bm = 0.f;
            if (EPI == 2) bm = bias[m];
#pragma unroll
            for (int ni = 0; ni < 4; ++ni) {
                const int nn = n0 + wn + ni * 16 + l15;
                float v = acc[mi][ni][r] * scale;
                if (EPI == 1) v = tanhf(v + bias[nn]);
                if (EPI == 2) v = tanhf(v + bm);
                if (F32OUT)
                    ((float*)OutV)[(size_t)nb * sO + (size_t)m * ldo + nn] = v;
                else
                    ((u16*)OutV)[(size_t)nb * sO + (size_t)m * ldo + nn] = f2bf(v);
            }
        }
    }
}

// ---- softmax over s (strided) of fp32 A(n,s,t), in place; coalesced in t ----
// Block: 64 t-columns, 256 threads. Thread (g = tid>>4, i = tid&15) owns
// columns 4i..4i+3 over s-chunk [g*64, g*64+64). Partial (m,l) merged in LDS.
__global__ __launch_bounds__(256) void softmax_cols(float* __restrict__ S) {
    __shared__ float pm[16][64];
    __shared__ float pl[16][64];
    __shared__ float fM[64];
    __shared__ float fR[64];
    const int n   = blockIdx.y;
    const int t0  = blockIdx.x * 64;
    const int tid = threadIdx.x;
    const int g   = tid >> 4;         // s-chunk 0..15
    const int ci  = (tid & 15) * 4;   // column quad within tile
    float* A = S + (size_t)n * T_D * T_D + t0 + ci;
    float* p = A + (size_t)g * 64 * T_D;

    float m[4] = {-1e30f, -1e30f, -1e30f, -1e30f};
    float l[4] = {0.f, 0.f, 0.f, 0.f};
#pragma unroll 8
    for (int s = 0; s < 64; ++s) {
        float4 v = *(const float4*)(p + (size_t)s * T_D);
        float x[4] = {v.x, v.y, v.z, v.w};
#pragma unroll
        for (int j = 0; j < 4; ++j) {
            float nm = fmaxf(m[j], x[j]);
            l[j] = l[j] * __expf(m[j] - nm) + __expf(x[j] - nm);
            m[j] = nm;
        }
    }
#pragma unroll
    for (int j = 0; j < 4; ++j) { pm[g][ci + j] = m[j]; pl[g][ci + j] = l[j]; }
    __syncthreads();
    if (tid < 64) {
        float M = -1e30f;
#pragma unroll
        for (int g2 = 0; g2 < 16; ++g2) M = fmaxf(M, pm[g2][tid]);
        float L = 0.f;
#pragma unroll
        for (int g2 = 0; g2 < 16; ++g2) L += pl[g2][tid] * __expf(pm[g2][tid] - M);
        fM[tid] = M;
        fR[tid] = 1.0f / L;
    }
    __syncthreads();
    float M[4], R[4];
#pragma unroll
    for (int j = 0; j < 4; ++j) { M[j] = fM[ci + j]; R[j] = fR[ci + j]; }
#pragma unroll 8
    for (int s = 0; s < 64; ++s) {
        float4 v = *(const float4*)(p + (size_t)s * T_D);
        v.x = __expf(v.x - M[0]) * R[0];
        v.y = __expf(v.y - M[1]) * R[1];
        v.z = __expf(v.z - M[2]) * R[2];
        v.w = __expf(v.w - M[3]) * R[3];
        *(float4*)(p + (size_t)s * T_D) = v;
    }
}

// ----- R GEMM: R(c,t) = sum_s Vp(c,s) * A(s,t);  Vp bf16, A fp32, R fp32 -----
// B-tile staged via LDS transpose (fp32 -> bf16).
__global__ __launch_bounds__(256) void gemm_r(
        const u16* __restrict__ Vp, const float* __restrict__ S,
        float* __restrict__ R)
{
    __shared__ __align__(16) u16 smA[128 * 32];
    __shared__ __align__(16) u16 smB[128 * 32];

    const int nb = blockIdx.z;
    const int n0 = blockIdx.x * 128;   // t
    const int m0 = blockIdx.y * 128;   // c
    const int tid = threadIdx.x;

    const u16* Ab = Vp + (size_t)nb * (C_D * T_D);
    const float* Sb = S + (size_t)nb * T_D * T_D;
    float* Rb = R + (size_t)nb * (C_D * T_D);

    const int srow = tid >> 2;
    const int sk8  = (tid & 3) * 8;
    const u16* gA0 = Ab + (size_t)(m0 + srow) * T_D + sk8;
    const u16* gA1 = gA0 + (size_t)64 * T_D;
    u16* lA0 = smA + tid * 8;
    u16* lA1 = smA + 2048 + tid * 8;

    // B transpose-staging map: sr = s-row in tile (0..31), tq*16 = t-base
    const int sr = tid >> 3;
    const int tq = (tid & 7) * 16;

    const int lane = tid & 63;
    const int w    = tid >> 6;
    const int wm   = (w >> 1) * 64;
    const int wn   = (w & 1) * 64;
    const int l15  = lane & 15;
    const int quad = lane >> 4;

    f32x4 acc[4][4];
#pragma unroll
    for (int i = 0; i < 4; ++i)
#pragma unroll
        for (int j = 0; j < 4; ++j) acc[i][j] = (f32x4){0.f, 0.f, 0.f, 0.f};

    for (int kb = 0; kb < T_D; kb += 32) {
        gld16(gA0 + kb, lA0);
        gld16(gA1 + kb, lA1);
        const float* srcB = Sb + (size_t)(kb + sr) * T_D + n0 + tq;
#pragma unroll
        for (int i = 0; i < 4; ++i) {
            float4 v = *(const float4*)(srcB + i * 4);
            smB[(tq + i * 4 + 0) * 32 + sr] = f2bf(v.x);
            smB[(tq + i * 4 + 1) * 32 + sr] = f2bf(v.y);
            smB[(tq + i * 4 + 2) * 32 + sr] = f2bf(v.z);
            smB[(tq + i * 4 + 3) * 32 + sr] = f2bf(v.w);
        }
        __syncthreads();
        short8 af[4], bfr[4];
#pragma unroll
        for (int i = 0; i < 4; ++i) {
            af[i]  = *(const short8*)(smA + (wm + i * 16 + l15) * 32 + quad * 8);
            bfr[i] = *(const short8*)(smB + (wn + i * 16 + l15) * 32 + quad * 8);
        }
#pragma unroll
        for (int mi = 0; mi < 4; ++mi)
#pragma unroll
            for (int ni = 0; ni < 4; ++ni)
                acc[mi][ni] = __builtin_amdgcn_mfma_f32_16x16x32_bf16(
                        af[mi], bfr[ni], acc[mi][ni], 0, 0, 0);
        __syncthreads();
    }

#pragma unroll
    for (int mi = 0; mi < 4; ++mi) {
        const int mb = m0 + wm + mi * 16 + quad * 4;
#pragma unroll
        for (int r = 0; r < 4; ++r) {
            const int m = mb + r;
#pragma unroll
            for (int ni = 0; ni < 4; ++ni) {
                const int nn = n0 + wn + ni * 16 + l15;
                Rb[(size_t)m * T_D + nn] = acc[mi][ni][r];
            }
        }
    }
}

extern "C" void kernel_launch(void* const* d_in, const int* in_sizes, int n_in,
                              void* d_out, int out_size, void* d_ws, size_t ws_size,
                              hipStream_t stream) {
    const float* Qf = (const float*)d_in[0];
    const float* Kf = (const float*)d_in[1];
    const float* Vf = (const float*)d_in[2];
    const float* Wq = (const float*)d_in[3];
    const float* bq = (const float*)d_in[4];
    const float* Wk = (const float*)d_in[5];
    const float* bk = (const float*)d_in[6];
    const float* Wv = (const float*)d_in[7];
    const float* bv = (const float*)d_in[8];

    float* Rout = (float*)d_out;                       // (n,c,t) fp32, 33.5 MB
    float* Aout = Rout + (size_t)N_B * C_D * T_D;      // (n,s,t) fp32, 134 MB

    // phase-1 scratch (all dead before their regions are overwritten):
    u16* QT  = (u16*)Rout;                 // bf16 (n,t,c), 16MB, in R region
    u16* KT  = (u16*)Rout + 8388608;       // bf16 (n,s,c), 16MB, in R region
    u16* VT  = (u16*)Aout;                 // bf16 (n,s,c), 16MB, in A region
    u16* Wqb = (u16*)Aout + 8388608;       // bf16 weights after VT
    u16* Wkb = Wqb + 65536;
    u16* Wvb = Wkb + 65536;
    // projections overwrite the consumed fp32 input buffers
    u16* QpT = (u16*)d_in[0];              // bf16 (n,t,c)
    u16* KpT = (u16*)d_in[1];              // bf16 (n,s,c)
    u16* Vp  = (u16*)d_in[2];              // bf16 (n,c,s)

    dim3 blk(256);
    const long sX = (long)T_D * C_D;   // 262144 elements
    const long sS = (long)T_D * T_D;   // 1048576 elements

    // 1) convert+transpose inputs fp32 -> bf16
    ct_f2b<<<dim3(16, 4, N_B), blk, 0, stream>>>(Qf, QT);
    ct_f2b<<<dim3(16, 4, N_B), blk, 0, stream>>>(Kf, KT);
    ct_f2b<<<dim3(16, 4, N_B), blk, 0, stream>>>(Vf, VT);
    // 2) convert weights
    conv_f2b<<<dim3(256), blk, 0, stream>>>(Wq, Wqb, 65536);
    conv_f2b<<<dim3(256), blk, 0, stream>>>(Wk, Wkb, 65536);
    conv_f2b<<<dim3(256), blk, 0, stream>>>(Wv, Wvb, 65536);

    // 3) projections (bf16 out into consumed input buffers)
    gemm_abt<1, false><<<dim3(2, 8, N_B), blk, 0, stream>>>(QT, Wqb, bq, QpT, C_D, C_D, sX, 0, sX, 1.0f);
    gemm_abt<1, false><<<dim3(2, 8, N_B), blk, 0, stream>>>(KT, Wkb, bk, KpT, C_D, C_D, sX, 0, sX, 1.0f);
    gemm_abt<2, false><<<dim3(8, 2, N_B), blk, 0, stream>>>(Wvb, VT, bv, Vp, C_D, T_D, 0, sX, sX, 1.0f);

    // 4) scores: S(s,t) = KpT(s,c) . QpT(t,c)^T / 16 -> fp32 straight into A output
    //    (overwrites VT + converted weights, both dead)
    gemm_abt<0, true><<<dim3(8, 8, N_B), blk, 0, stream>>>(KpT, QpT, nullptr, Aout, C_D, T_D, sX, sX, sS, 0.0625f);

    // 5) softmax over s (s-split 16-way per block, 64 cols/block), in place
    softmax_cols<<<dim3(16, N_B), blk, 0, stream>>>(Aout);

    // 6) R(c,t) = Vp(c,s) . A(s,t) -> fp32 (overwrites dead QT/KT)
    gemm_r<<<dim3(8, 2, N_B), blk, 0, stream>>>(Vp, Aout, Rout);
}

// Round 2
// 418.843 us; speedup vs baseline: 1.8203x; 1.1007x over previous
//
#include <hip/hip_runtime.h>
#include <stdint.h>

#define N_B 32
#define C_D 256
#define T_D 1024

typedef unsigned short u16;
typedef __attribute__((ext_vector_type(8))) short short8;
typedef __attribute__((ext_vector_type(4))) float f32x4;

__device__ __forceinline__ u16 f2bf(float f) {
    unsigned x = __float_as_uint(f);
    return (u16)((x + 0x7fffu + ((x >> 16) & 1u)) >> 16);  // RNE
}

__device__ __forceinline__ void gld16(const void* g, void* l) {
    __builtin_amdgcn_global_load_lds(
        (const __attribute__((address_space(1))) uint32_t*)g,
        (__attribute__((address_space(3))) uint32_t*)l, 16, 0, 0);
}

// ---- weights: 3x (256x256) fp32 -> bf16, one launch ----
__global__ __launch_bounds__(256) void conv_w(const float* __restrict__ w0,
                                              const float* __restrict__ w1,
                                              const float* __restrict__ w2,
                                              u16* __restrict__ o0,
                                              u16* __restrict__ o1,
                                              u16* __restrict__ o2) {
    const float* in = blockIdx.y == 0 ? w0 : (blockIdx.y == 1 ? w1 : w2);
    u16* out       = blockIdx.y == 0 ? o0 : (blockIdx.y == 1 ? o1 : o2);
    int i = blockIdx.x * 256 + threadIdx.x;
    out[i] = f2bf(in[i]);
}

// ---- staged transpose+convert: fp32 k-major source (row stride T_D) -> LDS
// 128(col) x 32(k) bf16 tile. Thread (tid>>4)=k-pair, (tid&15)*8=col base.
// Swizzle: element (t,k) stored at t*32 + (k ^ (((t>>4)&3)<<3)); packed u32
// writes (k even, k+1 odd) -> 4-way bank conflict instead of 16-way.
__device__ __forceinline__ void stage_tr(const float* __restrict__ src,
                                         u16* __restrict__ sm, int tid) {
    const int sr2 = tid >> 4;
    const int tt8 = (tid & 15) * 8;
    float4 v0 = *(const float4*)(src);
    float4 v1 = *(const float4*)(src + 4);
    float4 w0 = *(const float4*)(src + T_D);
    float4 w1 = *(const float4*)(src + T_D + 4);
    float a[8] = {v0.x, v0.y, v0.z, v0.w, v1.x, v1.y, v1.z, v1.w};
    float b[8] = {w0.x, w0.y, w0.z, w0.w, w1.x, w1.y, w1.z, w1.w};
    const int kk = sr2 * 2;
#pragma unroll
    for (int j = 0; j < 8; ++j) {
        const int t  = tt8 + j;
        const int ks = kk ^ (((t >> 4) & 3) << 3);
        uint32_t pk = (uint32_t)f2bf(a[j]) | ((uint32_t)f2bf(b[j]) << 16);
        *(uint32_t*)(sm + t * 32 + ks) = pk;
    }
}

// --------- unified GEMM: Out[m,n] = epi(scale * sum_k A[m,k]*B[n,k]) -------
// TRA/TRB: that side is fp32 k-major (row stride T_D), transposed+converted
// at staging. Otherwise bf16 rows K-contig (stride Kdim), gld16-staged.
// EPI: 0 = scale only; 1 = tanh(x + bias[n]); 2 = tanh(x + bias[m])
template <bool TRA, bool TRB, int EPI, bool F32OUT>
__global__ __launch_bounds__(256) void gemm_t(
        const void* __restrict__ Av, const void* __restrict__ Bv,
        const float* __restrict__ bias, void* __restrict__ OutV,
        int Kdim, int ldo, long sA, long sB, long sO, float scale)
{
    __shared__ __align__(16) u16 smA[128 * 32];
    __shared__ __align__(16) u16 smB[128 * 32];

    const int nb = blockIdx.z;
    const int n0 = blockIdx.x * 128;
    const int m0 = blockIdx.y * 128;
    const int tid = threadIdx.x;

    const int srow = tid >> 2;
    const int sk8  = (tid & 3) * 8;
    const int sr2  = tid >> 4;
    const int tt8  = (tid & 15) * 8;

    const u16* gA0 = nullptr; const u16* gA1 = nullptr;
    const float* tA = nullptr;
    if constexpr (TRA) {
        tA = (const float*)Av + (size_t)nb * sA + (size_t)(sr2 * 2) * T_D + m0 + tt8;
    } else {
        const u16* Ab = (const u16*)Av + (size_t)nb * sA;
        gA0 = Ab + (size_t)(m0 + srow) * Kdim + sk8;
        gA1 = gA0 + (size_t)64 * Kdim;
    }
    const u16* gB0 = nullptr; const u16* gB1 = nullptr;
    const float* tB = nullptr;
    if constexpr (TRB) {
        tB = (const float*)Bv + (size_t)nb * sB + (size_t)(sr2 * 2) * T_D + n0 + tt8;
    } else {
        const u16* Bb = (const u16*)Bv + (size_t)nb * sB;
        gB0 = Bb + (size_t)(n0 + srow) * Kdim + sk8;
        gB1 = gB0 + (size_t)64 * Kdim;
    }
    u16* lA0 = smA + tid * 8; u16* lA1 = smA + 2048 + tid * 8;
    u16* lB0 = smB + tid * 8; u16* lB1 = smB + 2048 + tid * 8;

    const int lane = tid & 63;
    const int w    = tid >> 6;
    const int wm   = (w >> 1) * 64;
    const int wn   = (w & 1) * 64;
    const int l15  = lane & 15;
    const int quad = lane >> 4;

    f32x4 acc[4][4];
#pragma unroll
    for (int i = 0; i < 4; ++i)
#pragma unroll
        for (int j = 0; j < 4; ++j) acc[i][j] = (f32x4){0.f, 0.f, 0.f, 0.f};

    for (int kb = 0; kb < Kdim; kb += 32) {
        if constexpr (TRA) {
            stage_tr(tA + (size_t)kb * T_D, smA, tid);
        } else {
            gld16(gA0 + kb, lA0);
            gld16(gA1 + kb, lA1);
        }
        if constexpr (TRB) {
            stage_tr(tB + (size_t)kb * T_D, smB, tid);
        } else {
            gld16(gB0 + kb, lB0);
            gld16(gB1 + kb, lB1);
        }
        __syncthreads();
        short8 af[4], bfr[4];
#pragma unroll
        for (int i = 0; i < 4; ++i) {
            const int ra = wm + i * 16 + l15;
            const int ca = TRA ? ((quad ^ ((ra >> 4) & 3)) * 8) : (quad * 8);
            af[i] = *(const short8*)(smA + ra * 32 + ca);
            const int rb = wn + i * 16 + l15;
            const int cb = TRB ? ((quad ^ ((rb >> 4) & 3)) * 8) : (quad * 8);
            bfr[i] = *(const short8*)(smB + rb * 32 + cb);
        }
#pragma unroll
        for (int mi = 0; mi < 4; ++mi)
#pragma unroll
            for (int ni = 0; ni < 4; ++ni)
                acc[mi][ni] = __builtin_amdgcn_mfma_f32_16x16x32_bf16(
                        af[mi], bfr[ni], acc[mi][ni], 0, 0, 0);
        __syncthreads();
    }

#pragma unroll
    for (int mi = 0; mi < 4; ++mi) {
        const int mb = m0 + wm + mi * 16 + quad * 4;
#pragma unroll
        for (int r = 0; r < 4; ++r) {
            const int m = mb + r;
            float bm = 0.f;
            if (EPI == 2) bm = bias[m];
#pragma unroll
            for (int ni = 0; ni < 4; ++ni) {
                const int nn = n0 + wn + ni * 16 + l15;
                float v = acc[mi][ni][r] * scale;
                if (EPI == 1) v = tanhf(v + bias[nn]);
                if (EPI == 2) v = tanhf(v + bm);
                if (F32OUT)
                    ((float*)OutV)[(size_t)nb * sO + (size_t)m * ldo + nn] = v;
                else
                    ((u16*)OutV)[(size_t)nb * sO + (size_t)m * ldo + nn] = f2bf(v);
            }
        }
    }
}

// ---- softmax over s (strided) of fp32 A(n,s,t), in place; coalesced in t ----
// Block: 64 t-columns, 256 threads. Thread (g = tid>>4, i = tid&15) owns
// columns 4i..4i+3 over s-chunk [g*64, g*64+64). Partial (m,l) merged in LDS.
__global__ __launch_bounds__(256) void softmax_cols(float* __restrict__ S) {
    __shared__ float pm[16][64];
    __shared__ float pl[16][64];
    __shared__ float fM[64];
    __shared__ float fR[64];
    const int n   = blockIdx.y;
    const int t0  = blockIdx.x * 64;
    const int tid = threadIdx.x;
    const int g   = tid >> 4;         // s-chunk 0..15
    const int ci  = (tid & 15) * 4;   // column quad within tile
    float* A = S + (size_t)n * T_D * T_D + t0 + ci;
    float* p = A + (size_t)g * 64 * T_D;

    float m[4] = {-1e30f, -1e30f, -1e30f, -1e30f};
    float l[4] = {0.f, 0.f, 0.f, 0.f};
#pragma unroll 8
    for (int s = 0; s < 64; ++s) {
        float4 v = *(const float4*)(p + (size_t)s * T_D);
        float x[4] = {v.x, v.y, v.z, v.w};
#pragma unroll
        for (int j = 0; j < 4; ++j) {
            float nm = fmaxf(m[j], x[j]);
            l[j] = l[j] * __expf(m[j] - nm) + __expf(x[j] - nm);
            m[j] = nm;
        }
    }
#pragma unroll
    for (int j = 0; j < 4; ++j) { pm[g][ci + j] = m[j]; pl[g][ci + j] = l[j]; }
    __syncthreads();
    if (tid < 64) {
        float M = -1e30f;
#pragma unroll
        for (int g2 = 0; g2 < 16; ++g2) M = fmaxf(M, pm[g2][tid]);
        float L = 0.f;
#pragma unroll
        for (int g2 = 0; g2 < 16; ++g2) L += pl[g2][tid] * __expf(pm[g2][tid] - M);
        fM[tid] = M;
        fR[tid] = 1.0f / L;
    }
    __syncthreads();
    float M[4], R[4];
#pragma unroll
    for (int j = 0; j < 4; ++j) { M[j] = fM[ci + j]; R[j] = fR[ci + j]; }
#pragma unroll 8
    for (int s = 0; s < 64; ++s) {
        float4 v = *(const float4*)(p + (size_t)s * T_D);
        v.x = __expf(v.x - M[0]) * R[0];
        v.y = __expf(v.y - M[1]) * R[1];
        v.z = __expf(v.z - M[2]) * R[2];
        v.w = __expf(v.w - M[3]) * R[3];
        *(float4*)(p + (size_t)s * T_D) = v;
    }
}

extern "C" void kernel_launch(void* const* d_in, const int* in_sizes, int n_in,
                              void* d_out, int out_size, void* d_ws, size_t ws_size,
                              hipStream_t stream) {
    const float* Qf = (const float*)d_in[0];
    const float* Kf = (const float*)d_in[1];
    const float* Vf = (const float*)d_in[2];
    const float* Wq = (const float*)d_in[3];
    const float* bq = (const float*)d_in[4];
    const float* Wk = (const float*)d_in[5];
    const float* bk = (const float*)d_in[6];
    const float* Wv = (const float*)d_in[7];
    const float* bv = (const float*)d_in[8];

    float* Rout = (float*)d_out;                       // (n,c,t) fp32, 33.5 MB
    float* Aout = Rout + (size_t)N_B * C_D * T_D;      // (n,s,t) fp32, 134 MB

    // scratch layout (stream order makes every aliasing safe):
    u16* QpT = (u16*)Rout;                 // bf16 (n,t,c), 16.8MB (R region)
    u16* KpT = (u16*)Rout + 8388608;       // bf16 (n,s,c), 16.8MB (R region)
    u16* Wqb = (u16*)Aout;                 // bf16 weights at head of A region
    u16* Wkb = Wqb + 65536;                //   (dead before scores writes A)
    u16* Wvb = Wkb + 65536;
    u16* Vp  = (u16*)d_in[0];              // bf16 (n,c,s) — Q consumed by then

    dim3 blk(256);
    const long sX = (long)C_D * T_D;   // 262144
    const long sS = (long)T_D * T_D;   // 1048576

    // 1) weights fp32 -> bf16 (one launch)
    conv_w<<<dim3(256, 3), blk, 0, stream>>>(Wq, Wk, Wv, Wqb, Wkb, Wvb);

    // 2) projections, transpose+convert fused into staging
    //    Qp^T(t,c) = tanh(Q^T Wq^T + bq): A = Q fp32 (c,t) transposed-staged
    gemm_t<true, false, 1, false><<<dim3(2, 8, N_B), blk, 0, stream>>>(
            Qf, Wqb, bq, QpT, C_D, C_D, sX, 0, sX, 1.0f);
    gemm_t<true, false, 1, false><<<dim3(2, 8, N_B), blk, 0, stream>>>(
            Kf, Wkb, bk, KpT, C_D, C_D, sX, 0, sX, 1.0f);
    //    Vp(c,s) = tanh(Wv V + bv): B = V fp32 (c,s) transposed-staged
    gemm_t<false, true, 2, false><<<dim3(8, 2, N_B), blk, 0, stream>>>(
            Wvb, Vf, bv, Vp, C_D, T_D, 0, sX, sX, 1.0f);

    // 3) scores: S(s,t) = KpT(s,:) . QpT(t,:) / 16 -> fp32 into A output
    gemm_t<false, false, 0, true><<<dim3(8, 8, N_B), blk, 0, stream>>>(
            KpT, QpT, nullptr, Aout, C_D, T_D, sX, sX, sS, 0.0625f);

    // 4) softmax over s, in place
    softmax_cols<<<dim3(16, N_B), blk, 0, stream>>>(Aout);

    // 5) R(c,t) = Vp(c,s) . A(s,t): B = A fp32 transposed-staged (swizzled)
    gemm_t<false, true, 0, true><<<dim3(8, 2, N_B), blk, 0, stream>>>(
            Vp, Aout, nullptr, Rout, T_D, T_D, sX, sS, sX, 1.0f);
}

// Round 3
// 418.830 us; speedup vs baseline: 1.8203x; 1.0000x over previous
//
#include <hip/hip_runtime.h>
#include <stdint.h>

#define N_B 32
#define C_D 256
#define T_D 1024

typedef unsigned short u16;
typedef __attribute__((ext_vector_type(8))) short short8;
typedef __attribute__((ext_vector_type(4))) float f32x4;

__device__ __forceinline__ u16 f2bf(float f) {
    unsigned x = __float_as_uint(f);
    return (u16)((x + 0x7fffu + ((x >> 16) & 1u)) >> 16);  // RNE
}

__device__ __forceinline__ void gld16(const void* g, void* l) {
    __builtin_amdgcn_global_load_lds(
        (const __attribute__((address_space(1))) uint32_t*)g,
        (__attribute__((address_space(3))) uint32_t*)l, 16, 0, 0);
}

// flash-style (m,l) merge: (m,l) <- combine((m,l),(m2,l2))
__device__ __forceinline__ void comb(float& m, float& l, float m2, float l2) {
    float M = fmaxf(m, m2);
    l = l * __expf(m - M) + l2 * __expf(m2 - M);
    m = M;
}

// ---- weights: 3x (256x256) fp32 -> bf16, one launch ----
__global__ __launch_bounds__(256) void conv_w(const float* __restrict__ w0,
                                              const float* __restrict__ w1,
                                              const float* __restrict__ w2,
                                              u16* __restrict__ o0,
                                              u16* __restrict__ o1,
                                              u16* __restrict__ o2) {
    const float* in = blockIdx.y == 0 ? w0 : (blockIdx.y == 1 ? w1 : w2);
    u16* out       = blockIdx.y == 0 ? o0 : (blockIdx.y == 1 ? o1 : o2);
    int i = blockIdx.x * 256 + threadIdx.x;
    out[i] = f2bf(in[i]);
}

// ---- staged transpose+convert: fp32 k-major source (row stride T_D) -> LDS
// 128(col) x 32(k) bf16 tile, XOR-swizzled (4-way conflict floor).
// NORM: apply y = exp(x - Mv[col])*Rv[col] and (if awr) write fp32 y to adst.
template <bool NORM>
__device__ __forceinline__ void stage_tr(const float* __restrict__ src,
                                         u16* __restrict__ sm, int tid,
                                         const float* Mv, const float* Rv,
                                         float* adst, bool awr) {
    const int sr2 = tid >> 4;
    const int tt8 = (tid & 15) * 8;
    float4 v0 = *(const float4*)(src);
    float4 v1 = *(const float4*)(src + 4);
    float4 w0 = *(const float4*)(src + T_D);
    float4 w1 = *(const float4*)(src + T_D + 4);
    float a[8] = {v0.x, v0.y, v0.z, v0.w, v1.x, v1.y, v1.z, v1.w};
    float b[8] = {w0.x, w0.y, w0.z, w0.w, w1.x, w1.y, w1.z, w1.w};
    if constexpr (NORM) {
#pragma unroll
        for (int j = 0; j < 8; ++j) {
            a[j] = __expf(a[j] - Mv[j]) * Rv[j];
            b[j] = __expf(b[j] - Mv[j]) * Rv[j];
        }
        if (awr) {
            ((float4*)adst)[0]         = make_float4(a[0], a[1], a[2], a[3]);
            ((float4*)adst)[1]         = make_float4(a[4], a[5], a[6], a[7]);
            ((float4*)(adst + T_D))[0] = make_float4(b[0], b[1], b[2], b[3]);
            ((float4*)(adst + T_D))[1] = make_float4(b[4], b[5], b[6], b[7]);
        }
    }
    const int kk = sr2 * 2;
#pragma unroll
    for (int j = 0; j < 8; ++j) {
        const int t  = tt8 + j;
        const int ks = kk ^ (((t >> 4) & 3) << 3);
        uint32_t pk = (uint32_t)f2bf(a[j]) | ((uint32_t)f2bf(b[j]) << 16);
        *(uint32_t*)(sm + t * 32 + ks) = pk;
    }
}

// --------- unified GEMM: Out[m,n] = epi(scale * sum_k A[m,k]*B[n,k]) -------
// TRA/TRB: that side is fp32 k-major (row stride T_D), transposed+converted
// at staging. Otherwise bf16 rows K-contig (stride Kdim), gld16-staged.
// EPI: 0 = scale only; 1 = tanh(x + bias[n]); 2 = tanh(x + bias[m]);
//      3 = scale + store fp32 + per-column (max,sumexp) partials to Pm/Pl.
// NORM (requires TRB): B-staging applies exp(x-Mf)*Rl; block m0==0 also
// writes the normalized fp32 values to Aw (the A output).
template <bool TRA, bool TRB, int EPI, bool F32OUT, bool NORM>
__global__ __launch_bounds__(256) void gemm_t(
        const void* __restrict__ Av, const void* __restrict__ Bv,
        const float* __restrict__ bias, void* __restrict__ OutV,
        int Kdim, int ldo, long sA, long sB, long sO, float scale,
        float* __restrict__ Pm, float* __restrict__ Pl,
        const float* __restrict__ Mf, const float* __restrict__ Rl,
        float* __restrict__ Aw)
{
    __shared__ __align__(16) u16 smA[128 * 32];
    __shared__ __align__(16) u16 smB[128 * 32];

    const int nb = blockIdx.z;
    const int n0 = blockIdx.x * 128;
    const int m0 = blockIdx.y * 128;
    const int tid = threadIdx.x;

    const int srow = tid >> 2;
    const int sk8  = (tid & 3) * 8;
    const int sr2  = tid >> 4;
    const int tt8  = (tid & 15) * 8;

    const u16* gA0 = nullptr; const u16* gA1 = nullptr;
    const float* tA = nullptr;
    if constexpr (TRA) {
        tA = (const float*)Av + (size_t)nb * sA + (size_t)(sr2 * 2) * T_D + m0 + tt8;
    } else {
        const u16* Ab = (const u16*)Av + (size_t)nb * sA;
        gA0 = Ab + (size_t)(m0 + srow) * Kdim + sk8;
        gA1 = gA0 + (size_t)64 * Kdim;
    }
    const u16* gB0 = nullptr; const u16* gB1 = nullptr;
    const float* tB = nullptr;
    if constexpr (TRB) {
        tB = (const float*)Bv + (size_t)nb * sB + (size_t)(sr2 * 2) * T_D + n0 + tt8;
    } else {
        const u16* Bb = (const u16*)Bv + (size_t)nb * sB;
        gB0 = Bb + (size_t)(n0 + srow) * Kdim + sk8;
        gB1 = gB0 + (size_t)64 * Kdim;
    }
    u16* lA0 = smA + tid * 8; u16* lA1 = smA + 2048 + tid * 8;
    u16* lB0 = smB + tid * 8; u16* lB1 = smB + 2048 + tid * 8;

    float Mv[8], Rv[8];
    float* awbase = nullptr;
    bool awr = false;
    if constexpr (NORM) {
#pragma unroll
        for (int j = 0; j < 8; ++j) {
            Mv[j] = Mf[(size_t)nb * T_D + n0 + tt8 + j];
            Rv[j] = Rl[(size_t)nb * T_D + n0 + tt8 + j];
        }
        awbase = Aw + (size_t)nb * sB + (size_t)(sr2 * 2) * T_D + n0 + tt8;
        awr = (blockIdx.y == 0);
    }

    const int lane = tid & 63;
    const int w    = tid >> 6;
    const int wm   = (w >> 1) * 64;
    const int wn   = (w & 1) * 64;
    const int l15  = lane & 15;
    const int quad = lane >> 4;

    f32x4 acc[4][4];
#pragma unroll
    for (int i = 0; i < 4; ++i)
#pragma unroll
        for (int j = 0; j < 4; ++j) acc[i][j] = (f32x4){0.f, 0.f, 0.f, 0.f};

    for (int kb = 0; kb < Kdim; kb += 32) {
        if constexpr (TRA) {
            stage_tr<false>(tA + (size_t)kb * T_D, smA, tid, nullptr, nullptr, nullptr, false);
        } else {
            gld16(gA0 + kb, lA0);
            gld16(gA1 + kb, lA1);
        }
        if constexpr (TRB) {
            if constexpr (NORM)
                stage_tr<true>(tB + (size_t)kb * T_D, smB, tid, Mv, Rv,
                               awbase + (size_t)kb * T_D, awr);
            else
                stage_tr<false>(tB + (size_t)kb * T_D, smB, tid, nullptr, nullptr, nullptr, false);
        } else {
            gld16(gB0 + kb, lB0);
            gld16(gB1 + kb, lB1);
        }
        __syncthreads();
        short8 af[4], bfr[4];
#pragma unroll
        for (int i = 0; i < 4; ++i) {
            const int ra = wm + i * 16 + l15;
            const int ca = TRA ? ((quad ^ ((ra >> 4) & 3)) * 8) : (quad * 8);
            af[i] = *(const short8*)(smA + ra * 32 + ca);
            const int rb = wn + i * 16 + l15;
            const int cb = TRB ? ((quad ^ ((rb >> 4) & 3)) * 8) : (quad * 8);
            bfr[i] = *(const short8*)(smB + rb * 32 + cb);
        }
#pragma unroll
        for (int mi = 0; mi < 4; ++mi)
#pragma unroll
            for (int ni = 0; ni < 4; ++ni)
                acc[mi][ni] = __builtin_amdgcn_mfma_f32_16x16x32_bf16(
                        af[mi], bfr[ni], acc[mi][ni], 0, 0, 0);
        __syncthreads();
    }

    if constexpr (EPI == 3) {
        // store fp32 S + per-column (over the block's 128 rows) max/sumexp
        float pmv[4] = {-1e30f, -1e30f, -1e30f, -1e30f};
        float plv[4] = {0.f, 0.f, 0.f, 0.f};
#pragma unroll
        for (int mi = 0; mi < 4; ++mi) {
            const int mb = m0 + wm + mi * 16 + quad * 4;
#pragma unroll
            for (int r = 0; r < 4; ++r) {
                const int m = mb + r;
#pragma unroll
                for (int ni = 0; ni < 4; ++ni) {
                    const int nn = n0 + wn + ni * 16 + l15;
                    float v = acc[mi][ni][r] * scale;
                    ((float*)OutV)[(size_t)nb * sO + (size_t)m * ldo + nn] = v;
                    pmv[ni] = fmaxf(pmv[ni], v);
                }
            }
        }
#pragma unroll
        for (int ni = 0; ni < 4; ++ni) {
            float s = 0.f;
#pragma unroll
            for (int mi = 0; mi < 4; ++mi)
#pragma unroll
                for (int r = 0; r < 4; ++r)
                    s += __expf(acc[mi][ni][r] * scale - pmv[ni]);
            plv[ni] = s;
        }
#pragma unroll
        for (int ni = 0; ni < 4; ++ni) {
            float m = pmv[ni], l = plv[ni];
            float m2 = __shfl_xor(m, 16), l2 = __shfl_xor(l, 16);
            comb(m, l, m2, l2);
            m2 = __shfl_xor(m, 32); l2 = __shfl_xor(l, 32);
            comb(m, l, m2, l2);
            pmv[ni] = m; plv[ni] = l;
        }
        __shared__ float red_m[4][64];
        __shared__ float red_l[4][64];
        if (quad == 0) {
#pragma unroll
            for (int ni = 0; ni < 4; ++ni) {
                red_m[w][ni * 16 + l15] = pmv[ni];
                red_l[w][ni * 16 + l15] = plv[ni];
            }
        }
        __syncthreads();
        if (tid < 128) {
            const int half = tid >> 6, cc = tid & 63;
            float m = red_m[half][cc], l = red_l[half][cc];
            comb(m, l, red_m[half + 2][cc], red_l[half + 2][cc]);
            const size_t pi = ((size_t)nb * 8 + blockIdx.y) * T_D + n0 + tid;
            Pm[pi] = m; Pl[pi] = l;
        }
    } else {
#pragma unroll
        for (int mi = 0; mi < 4; ++mi) {
            const int mb = m0 + wm + mi * 16 + quad * 4;
#pragma unroll
            for (int r = 0; r < 4; ++r) {
                const int m = mb + r;
                float bm = 0.f;
                if (EPI == 2) bm = bias[m];
#pragma unroll
                for (int ni = 0; ni < 4; ++ni) {
                    const int nn = n0 + wn + ni * 16 + l15;
                    float v = acc[mi][ni][r] * scale;
                    if (EPI == 1) v = tanhf(v + bias[nn]);
                    if (EPI == 2) v = tanhf(v + bm);
                    if (F32OUT)
                        ((float*)OutV)[(size_t)nb * sO + (size_t)m * ldo + nn] = v;
                    else
                        ((u16*)OutV)[(size_t)nb * sO + (size_t)m * ldo + nn] = f2bf(v);
                }
            }
        }
    }
}

// ---- merge per-s-tile partials: M = max, Rl = 1/sum(l*exp(m-M)) ----
__global__ __launch_bounds__(256) void merge_ml(const float* __restrict__ Pm,
                                                const float* __restrict__ Pl,
                                                float* __restrict__ Mf,
                                                float* __restrict__ Rl) {
    const int i = blockIdx.x * 256 + threadIdx.x;  // over N_B*T_D
    const int n = i >> 10, t = i & (T_D - 1);
    const float* pm = Pm + (size_t)n * 8 * T_D + t;
    const float* pl = Pl + (size_t)n * 8 * T_D + t;
    float M = -1e30f;
#pragma unroll
    for (int j = 0; j < 8; ++j) M = fmaxf(M, pm[(size_t)j * T_D]);
    float L = 0.f;
#pragma unroll
    for (int j = 0; j < 8; ++j) L += pl[(size_t)j * T_D] * __expf(pm[(size_t)j * T_D] - M);
    Mf[i] = M;
    Rl[i] = 1.0f / L;
}

// ---- elementwise normalize (Path B): A = exp(S - M[t]) * Rl[t], in place ----
__global__ __launch_bounds__(256) void norm_a(float* __restrict__ S,
                                              const float* __restrict__ Mf,
                                              const float* __restrict__ Rl) {
    const size_t i = ((size_t)blockIdx.x * 256 + threadIdx.x) * 4;
    const int n = (int)(i >> 20);
    const int t = (int)(i & (T_D - 1));
    float4 M = *(const float4*)(Mf + (size_t)n * T_D + t);
    float4 R = *(const float4*)(Rl + (size_t)n * T_D + t);
    float4 v = *(float4*)(S + i);
    v.x = __expf(v.x - M.x) * R.x;
    v.y = __expf(v.y - M.y) * R.y;
    v.z = __expf(v.z - M.z) * R.z;
    v.w = __expf(v.w - M.w) * R.w;
    *(float4*)(S + i) = v;
}

// ---- Path C fallback: softmax over s of fp32 A(n,s,t), in place ----
__global__ __launch_bounds__(256) void softmax_cols(float* __restrict__ S) {
    __shared__ float pm[16][64];
    __shared__ float pl[16][64];
    __shared__ float fM[64];
    __shared__ float fR[64];
    const int n   = blockIdx.y;
    const int t0  = blockIdx.x * 64;
    const int tid = threadIdx.x;
    const int g   = tid >> 4;
    const int ci  = (tid & 15) * 4;
    float* A = S + (size_t)n * T_D * T_D + t0 + ci;
    float* p = A + (size_t)g * 64 * T_D;

    float m[4] = {-1e30f, -1e30f, -1e30f, -1e30f};
    float l[4] = {0.f, 0.f, 0.f, 0.f};
#pragma unroll 8
    for (int s = 0; s < 64; ++s) {
        float4 v = *(const float4*)(p + (size_t)s * T_D);
        float x[4] = {v.x, v.y, v.z, v.w};
#pragma unroll
        for (int j = 0; j < 4; ++j) {
            float nm = fmaxf(m[j], x[j]);
            l[j] = l[j] * __expf(m[j] - nm) + __expf(x[j] - nm);
            m[j] = nm;
        }
    }
#pragma unroll
    for (int j = 0; j < 4; ++j) { pm[g][ci + j] = m[j]; pl[g][ci + j] = l[j]; }
    __syncthreads();
    if (tid < 64) {
        float M = -1e30f;
#pragma unroll
        for (int g2 = 0; g2 < 16; ++g2) M = fmaxf(M, pm[g2][tid]);
        float L = 0.f;
#pragma unroll
        for (int g2 = 0; g2 < 16; ++g2) L += pl[g2][tid] * __expf(pm[g2][tid] - M);
        fM[tid] = M;
        fR[tid] = 1.0f / L;
    }
    __syncthreads();
    float M[4], R[4];
#pragma unroll
    for (int j = 0; j < 4; ++j) { M[j] = fM[ci + j]; R[j] = fR[ci + j]; }
#pragma unroll 8
    for (int s = 0; s < 64; ++s) {
        float4 v = *(const float4*)(p + (size_t)s * T_D);
        v.x = __expf(v.x - M[0]) * R[0];
        v.y = __expf(v.y - M[1]) * R[1];
        v.z = __expf(v.z - M[2]) * R[2];
        v.w = __expf(v.w - M[3]) * R[3];
        *(float4*)(p + (size_t)s * T_D) = v;
    }
}

extern "C" void kernel_launch(void* const* d_in, const int* in_sizes, int n_in,
                              void* d_out, int out_size, void* d_ws, size_t ws_size,
                              hipStream_t stream) {
    const float* Qf = (const float*)d_in[0];
    const float* Kf = (const float*)d_in[1];
    const float* Vf = (const float*)d_in[2];
    const float* Wq = (const float*)d_in[3];
    const float* bq = (const float*)d_in[4];
    const float* Wk = (const float*)d_in[5];
    const float* bk = (const float*)d_in[6];
    const float* Wv = (const float*)d_in[7];
    const float* bv = (const float*)d_in[8];

    float* Rout = (float*)d_out;
    float* Aout = Rout + (size_t)N_B * C_D * T_D;

    u16* QpT = (u16*)Rout;                 // bf16 (n,t,c) in R region
    u16* KpT = (u16*)Rout + 8388608;       // bf16 (n,s,c) in R region
    u16* Wqb = (u16*)Aout;                 // weights at head of A region (dead
    u16* Wkb = Wqb + 65536;                //   before anything writes A)
    u16* Wvb = Wkb + 65536;
    u16* Vp  = (u16*)d_in[0];              // bf16 (n,c,s) — Q consumed by then

    dim3 blk(256);
    const long sX = (long)C_D * T_D;
    const long sS = (long)T_D * T_D;

    const size_t elemsS = (size_t)N_B * T_D * T_D;
    const size_t elemsP = (size_t)N_B * 8 * T_D;
    const size_t elemsM = (size_t)N_B * T_D;
    const size_t needA = (elemsS + 2 * elemsP + 2 * elemsM) * 4;
    const size_t needB = (2 * elemsP + 2 * elemsM) * 4;

    // 1) weights fp32 -> bf16
    conv_w<<<dim3(256, 3), blk, 0, stream>>>(Wq, Wk, Wv, Wqb, Wkb, Wvb);

    // 2) projections, transpose+convert fused into staging
    gemm_t<true, false, 1, false, false><<<dim3(2, 8, N_B), blk, 0, stream>>>(
            Qf, Wqb, bq, QpT, C_D, C_D, sX, 0, sX, 1.0f,
            nullptr, nullptr, nullptr, nullptr, nullptr);
    gemm_t<true, false, 1, false, false><<<dim3(2, 8, N_B), blk, 0, stream>>>(
            Kf, Wkb, bk, KpT, C_D, C_D, sX, 0, sX, 1.0f,
            nullptr, nullptr, nullptr, nullptr, nullptr);
    gemm_t<false, true, 2, false, false><<<dim3(8, 2, N_B), blk, 0, stream>>>(
            Wvb, Vf, bv, Vp, C_D, T_D, 0, sX, sX, 1.0f,
            nullptr, nullptr, nullptr, nullptr, nullptr);

    if (ws_size >= needA) {
        // Path A: S -> workspace; softmax fully fused into scores + gemm_r
        float* Sws = (float*)d_ws;
        float* Pm  = Sws + elemsS;
        float* Pl  = Pm + elemsP;
        float* Mf  = Pl + elemsP;
        float* Rl  = Mf + elemsM;
        gemm_t<false, false, 3, true, false><<<dim3(8, 8, N_B), blk, 0, stream>>>(
                KpT, QpT, nullptr, Sws, C_D, T_D, sX, sX, sS, 0.0625f,
                Pm, Pl, nullptr, nullptr, nullptr);
        merge_ml<<<dim3(128), blk, 0, stream>>>(Pm, Pl, Mf, Rl);
        gemm_t<false, true, 0, true, true><<<dim3(8, 2, N_B), blk, 0, stream>>>(
                Vp, Sws, nullptr, Rout, T_D, T_D, sX, sS, sX, 1.0f,
                nullptr, nullptr, Mf, Rl, Aout);
    } else if (ws_size >= needB) {
        // Path B: S in Aout; partials in ws; elementwise normalize
        float* Pm = (float*)d_ws;
        float* Pl = Pm + elemsP;
        float* Mf = Pl + elemsP;
        float* Rl = Mf + elemsM;
        gemm_t<false, false, 3, true, false><<<dim3(8, 8, N_B), blk, 0, stream>>>(
                KpT, QpT, nullptr, Aout, C_D, T_D, sX, sX, sS, 0.0625f,
                Pm, Pl, nullptr, nullptr, nullptr);
        merge_ml<<<dim3(128), blk, 0, stream>>>(Pm, Pl, Mf, Rl);
        norm_a<<<dim3(32768), blk, 0, stream>>>(Aout, Mf, Rl);
        gemm_t<false, true, 0, true, false><<<dim3(8, 2, N_B), blk, 0, stream>>>(
                Vp, Aout, nullptr, Rout, T_D, T_D, sX, sS, sX, 1.0f,
                nullptr, nullptr, nullptr, nullptr, nullptr);
    } else {
        // Path C: round-2 flow
        gemm_t<false, false, 0, true, false><<<dim3(8, 8, N_B), blk, 0, stream>>>(
                KpT, QpT, nullptr, Aout, C_D, T_D, sX, sX, sS, 0.0625f,
                nullptr, nullptr, nullptr, nullptr, nullptr);
        softmax_cols<<<dim3(16, N_B), blk, 0, stream>>>(Aout);
        gemm_t<false, true, 0, true, false><<<dim3(8, 2, N_B), blk, 0, stream>>>(
                Vp, Aout, nullptr, Rout, T_D, T_D, sX, sS, sX, 1.0f,
                nullptr, nullptr, nullptr, nullptr, nullptr);
    }
}

// Round 4
// 389.723 us; speedup vs baseline: 1.9563x; 1.0747x over previous
//
#include <hip/hip_runtime.h>
#include <stdint.h>

#define N_B 32
#define C_D 256
#define T_D 1024

typedef unsigned short u16;
typedef __attribute__((ext_vector_type(8))) short short8;
typedef __attribute__((ext_vector_type(4))) float f32x4;

__device__ __forceinline__ u16 f2bf(float f) {
    unsigned x = __float_as_uint(f);
    return (u16)((x + 0x7fffu + ((x >> 16) & 1u)) >> 16);  // RNE
}

__device__ __forceinline__ void gld16(const void* g, void* l) {
    __builtin_amdgcn_global_load_lds(
        (const __attribute__((address_space(1))) uint32_t*)g,
        (__attribute__((address_space(3))) uint32_t*)l, 16, 0, 0);
}

// flash-style (m,l) merge
__device__ __forceinline__ void comb(float& m, float& l, float m2, float l2) {
    float M = fmaxf(m, m2);
    l = l * __expf(m - M) + l2 * __expf(m2 - M);
    m = M;
}

// ---- weights: 3x (256x256) fp32 -> bf16, one launch ----
__global__ __launch_bounds__(256) void conv_w(const float* __restrict__ w0,
                                              const float* __restrict__ w1,
                                              const float* __restrict__ w2,
                                              u16* __restrict__ o0,
                                              u16* __restrict__ o1,
                                              u16* __restrict__ o2) {
    const float* in = blockIdx.y == 0 ? w0 : (blockIdx.y == 1 ? w1 : w2);
    u16* out       = blockIdx.y == 0 ? o0 : (blockIdx.y == 1 ? o1 : o2);
    int i = blockIdx.x * 256 + threadIdx.x;
    out[i] = f2bf(in[i]);
}

// ---- staged transpose+convert: fp32 k-major source (row stride T_D) -> LDS
// 128(col) x 32(k) bf16 tile, XOR-swizzled (4-way conflict floor).
// NORM: y = exp(x - Mv[col])*Rv[col]; if awr, write fp32 y back to adst
// (adst MAY alias src — no __restrict__ here; loads precede stores).
template <bool NORM>
__device__ __forceinline__ void stage_tr(const float* src, u16* sm, int tid,
                                         const float* Mv, const float* Rv,
                                         float* adst, bool awr) {
    const int sr2 = tid >> 4;
    const int tt8 = (tid & 15) * 8;
    float4 v0 = *(const float4*)(src);
    float4 v1 = *(const float4*)(src + 4);
    float4 w0 = *(const float4*)(src + T_D);
    float4 w1 = *(const float4*)(src + T_D + 4);
    float a[8] = {v0.x, v0.y, v0.z, v0.w, v1.x, v1.y, v1.z, v1.w};
    float b[8] = {w0.x, w0.y, w0.z, w0.w, w1.x, w1.y, w1.z, w1.w};
    if constexpr (NORM) {
#pragma unroll
        for (int j = 0; j < 8; ++j) {
            a[j] = __expf(a[j] - Mv[j]) * Rv[j];
            b[j] = __expf(b[j] - Mv[j]) * Rv[j];
        }
        if (awr) {
            ((float4*)adst)[0]         = make_float4(a[0], a[1], a[2], a[3]);
            ((float4*)adst)[1]         = make_float4(a[4], a[5], a[6], a[7]);
            ((float4*)(adst + T_D))[0] = make_float4(b[0], b[1], b[2], b[3]);
            ((float4*)(adst + T_D))[1] = make_float4(b[4], b[5], b[6], b[7]);
        }
    }
    const int kk = sr2 * 2;
#pragma unroll
    for (int j = 0; j < 8; ++j) {
        const int t  = tt8 + j;
        const int ks = kk ^ (((t >> 4) & 3) << 3);
        uint32_t pk = (uint32_t)f2bf(a[j]) | ((uint32_t)f2bf(b[j]) << 16);
        *(uint32_t*)(sm + t * 32 + ks) = pk;
    }
}

// --------- unified GEMM: Out[m,n] = epi(scale * sum_k A[m,k]*B[n,k]) -------
// TRA/TRB: that side is fp32 k-major (row stride T_D), transposed+converted
// at staging. Otherwise bf16 rows K-contig (stride Kdim), gld16-staged.
// EPI: 0 = scale only; 1 = tanh(x + bias[n]); 2 = tanh(x + bias[m]);
//      3 = scale + store fp32 + per-column (max,sumexp) partials to Pm/Pl.
template <bool TRA, bool TRB, int EPI, bool F32OUT>
__global__ __launch_bounds__(256) void gemm_t(
        const void* __restrict__ Av, const void* __restrict__ Bv,
        const float* __restrict__ bias, void* __restrict__ OutV,
        int Kdim, int ldo, long sA, long sB, long sO, float scale,
        float* __restrict__ Pm, float* __restrict__ Pl)
{
    __shared__ __align__(16) u16 smA[128 * 32];
    __shared__ __align__(16) u16 smB[128 * 32];

    const int nb = blockIdx.z;
    const int n0 = blockIdx.x * 128;
    const int m0 = blockIdx.y * 128;
    const int tid = threadIdx.x;

    const int srow = tid >> 2;
    const int sk8  = (tid & 3) * 8;
    const int sr2  = tid >> 4;
    const int tt8  = (tid & 15) * 8;

    const u16* gA0 = nullptr; const u16* gA1 = nullptr;
    const float* tA = nullptr;
    if constexpr (TRA) {
        tA = (const float*)Av + (size_t)nb * sA + (size_t)(sr2 * 2) * T_D + m0 + tt8;
    } else {
        const u16* Ab = (const u16*)Av + (size_t)nb * sA;
        gA0 = Ab + (size_t)(m0 + srow) * Kdim + sk8;
        gA1 = gA0 + (size_t)64 * Kdim;
    }
    const u16* gB0 = nullptr; const u16* gB1 = nullptr;
    const float* tB = nullptr;
    if constexpr (TRB) {
        tB = (const float*)Bv + (size_t)nb * sB + (size_t)(sr2 * 2) * T_D + n0 + tt8;
    } else {
        const u16* Bb = (const u16*)Bv + (size_t)nb * sB;
        gB0 = Bb + (size_t)(n0 + srow) * Kdim + sk8;
        gB1 = gB0 + (size_t)64 * Kdim;
    }
    u16* lA0 = smA + tid * 8; u16* lA1 = smA + 2048 + tid * 8;
    u16* lB0 = smB + tid * 8; u16* lB1 = smB + 2048 + tid * 8;

    const int lane = tid & 63;
    const int w    = tid >> 6;
    const int wm   = (w >> 1) * 64;
    const int wn   = (w & 1) * 64;
    const int l15  = lane & 15;
    const int quad = lane >> 4;

    f32x4 acc[4][4];
#pragma unroll
    for (int i = 0; i < 4; ++i)
#pragma unroll
        for (int j = 0; j < 4; ++j) acc[i][j] = (f32x4){0.f, 0.f, 0.f, 0.f};

    for (int kb = 0; kb < Kdim; kb += 32) {
        if constexpr (TRA) {
            stage_tr<false>(tA + (size_t)kb * T_D, smA, tid, nullptr, nullptr, nullptr, false);
        } else {
            gld16(gA0 + kb, lA0);
            gld16(gA1 + kb, lA1);
        }
        if constexpr (TRB) {
            stage_tr<false>(tB + (size_t)kb * T_D, smB, tid, nullptr, nullptr, nullptr, false);
        } else {
            gld16(gB0 + kb, lB0);
            gld16(gB1 + kb, lB1);
        }
        __syncthreads();
        short8 af[4], bfr[4];
#pragma unroll
        for (int i = 0; i < 4; ++i) {
            const int ra = wm + i * 16 + l15;
            const int ca = TRA ? ((quad ^ ((ra >> 4) & 3)) * 8) : (quad * 8);
            af[i] = *(const short8*)(smA + ra * 32 + ca);
            const int rb = wn + i * 16 + l15;
            const int cb = TRB ? ((quad ^ ((rb >> 4) & 3)) * 8) : (quad * 8);
            bfr[i] = *(const short8*)(smB + rb * 32 + cb);
        }
#pragma unroll
        for (int mi = 0; mi < 4; ++mi)
#pragma unroll
            for (int ni = 0; ni < 4; ++ni)
                acc[mi][ni] = __builtin_amdgcn_mfma_f32_16x16x32_bf16(
                        af[mi], bfr[ni], acc[mi][ni], 0, 0, 0);
        __syncthreads();
    }

    if constexpr (EPI == 3) {
        float pmv[4] = {-1e30f, -1e30f, -1e30f, -1e30f};
        float plv[4] = {0.f, 0.f, 0.f, 0.f};
#pragma unroll
        for (int mi = 0; mi < 4; ++mi) {
            const int mb = m0 + wm + mi * 16 + quad * 4;
#pragma unroll
            for (int r = 0; r < 4; ++r) {
                const int m = mb + r;
#pragma unroll
                for (int ni = 0; ni < 4; ++ni) {
                    const int nn = n0 + wn + ni * 16 + l15;
                    float v = acc[mi][ni][r] * scale;
                    ((float*)OutV)[(size_t)nb * sO + (size_t)m * ldo + nn] = v;
                    pmv[ni] = fmaxf(pmv[ni], v);
                }
            }
        }
#pragma unroll
        for (int ni = 0; ni < 4; ++ni) {
            float s = 0.f;
#pragma unroll
            for (int mi = 0; mi < 4; ++mi)
#pragma unroll
                for (int r = 0; r < 4; ++r)
                    s += __expf(acc[mi][ni][r] * scale - pmv[ni]);
            plv[ni] = s;
        }
#pragma unroll
        for (int ni = 0; ni < 4; ++ni) {
            float m = pmv[ni], l = plv[ni];
            float m2 = __shfl_xor(m, 16), l2 = __shfl_xor(l, 16);
            comb(m, l, m2, l2);
            m2 = __shfl_xor(m, 32); l2 = __shfl_xor(l, 32);
            comb(m, l, m2, l2);
            pmv[ni] = m; plv[ni] = l;
        }
        __shared__ float red_m[4][64];
        __shared__ float red_l[4][64];
        if (quad == 0) {
#pragma unroll
            for (int ni = 0; ni < 4; ++ni) {
                red_m[w][ni * 16 + l15] = pmv[ni];
                red_l[w][ni * 16 + l15] = plv[ni];
            }
        }
        __syncthreads();
        if (tid < 128) {
            const int half = tid >> 6, cc = tid & 63;
            float m = red_m[half][cc], l = red_l[half][cc];
            comb(m, l, red_m[half + 2][cc], red_l[half + 2][cc]);
            const size_t pi = ((size_t)nb * 8 + blockIdx.y) * T_D + n0 + tid;
            Pm[pi] = m; Pl[pi] = l;
        }
    } else {
#pragma unroll
        for (int mi = 0; mi < 4; ++mi) {
            const int mb = m0 + wm + mi * 16 + quad * 4;
#pragma unroll
            for (int r = 0; r < 4; ++r) {
                const int m = mb + r;
                float bm = 0.f;
                if (EPI == 2) bm = bias[m];
#pragma unroll
                for (int ni = 0; ni < 4; ++ni) {
                    const int nn = n0 + wn + ni * 16 + l15;
                    float v = acc[mi][ni][r] * scale;
                    if (EPI == 1) v = tanhf(v + bias[nn]);
                    if (EPI == 2) v = tanhf(v + bm);
                    if (F32OUT)
                        ((float*)OutV)[(size_t)nb * sO + (size_t)m * ldo + nn] = v;
                    else
                        ((u16*)OutV)[(size_t)nb * sO + (size_t)m * ldo + nn] = f2bf(v);
                }
            }
        }
    }
}

// ---- merge per-s-tile partials: M = max, Rl = 1/sum(l*exp(m-M)) ----
__global__ __launch_bounds__(256) void merge_ml(const float* __restrict__ Pm,
                                                const float* __restrict__ Pl,
                                                float* __restrict__ Mf,
                                                float* __restrict__ Rl) {
    const int i = blockIdx.x * 256 + threadIdx.x;  // over N_B*T_D
    const int n = i >> 10, t = i & (T_D - 1);
    const float* pm = Pm + (size_t)n * 8 * T_D + t;
    const float* pl = Pl + (size_t)n * 8 * T_D + t;
    float M = -1e30f;
#pragma unroll
    for (int j = 0; j < 8; ++j) M = fmaxf(M, pm[(size_t)j * T_D]);
    float L = 0.f;
#pragma unroll
    for (int j = 0; j < 8; ++j) L += pl[(size_t)j * T_D] * __expf(pm[(size_t)j * T_D] - M);
    Mf[i] = M;
    Rl[i] = 1.0f / L;
}

// ----- fused R GEMM: R(c,t) = sum_s Vp(c,s) * A(s,t), A = exp(S-M)*rL -----
// BM=256 (all c), BN=128; 512 threads / 8 waves; grid (8,1,N_B).
// Each block exclusively owns its (nb, t-panel) of S: staging reads raw S,
// normalizes, writes fp32 A back IN PLACE, and feeds bf16 fragments to MFMA.
__global__ __launch_bounds__(512) void gemm_rn(
        const u16* __restrict__ Vp, float* S,
        const float* __restrict__ Mf, const float* __restrict__ Rl,
        float* __restrict__ R)
{
    __shared__ __align__(16) u16 smA[256 * 32];   // 16 KB
    __shared__ __align__(16) u16 smB[128 * 32];   // 8 KB

    const int nb  = blockIdx.z;
    const int n0  = blockIdx.x * 128;
    const int tid = threadIdx.x;

    const u16* Ab = Vp + (size_t)nb * (C_D * T_D);
    float* Sb = S + (size_t)nb * ((size_t)T_D * T_D);
    float* Rb = R + (size_t)nb * (C_D * T_D);

    const int srow = tid >> 2;        // 0..127
    const int sk8  = (tid & 3) * 8;
    const u16* gA0 = Ab + (size_t)srow * T_D + sk8;
    const u16* gA1 = gA0 + (size_t)128 * T_D;
    u16* lA0 = smA + tid * 8;
    u16* lA1 = smA + 4096 + tid * 8;

    float Mv[8], Rv[8];
    float* tB = nullptr;
    if (tid < 256) {
        const int sr2 = tid >> 4;
        const int tt8 = (tid & 15) * 8;
        tB = Sb + (size_t)(sr2 * 2) * T_D + n0 + tt8;
#pragma unroll
        for (int j = 0; j < 8; ++j) {
            Mv[j] = Mf[(size_t)nb * T_D + n0 + tt8 + j];
            Rv[j] = Rl[(size_t)nb * T_D + n0 + tt8 + j];
        }
    }

    const int lane = tid & 63;
    const int w    = tid >> 6;        // 0..7
    const int wm   = (w >> 1) * 64;   // 0,64,128,192
    const int wn   = (w & 1) * 64;    // 0,64
    const int l15  = lane & 15;
    const int quad = lane >> 4;

    f32x4 acc[4][4];
#pragma unroll
    for (int i = 0; i < 4; ++i)
#pragma unroll
        for (int j = 0; j < 4; ++j) acc[i][j] = (f32x4){0.f, 0.f, 0.f, 0.f};

    for (int kb = 0; kb < T_D; kb += 32) {
        gld16(gA0 + kb, lA0);
        gld16(gA1 + kb, lA1);
        if (tid < 256) {
            float* src = tB + (size_t)kb * T_D;
            stage_tr<true>(src, smB, tid, Mv, Rv, src, true);
        }
        __syncthreads();
        short8 af[4], bfr[4];
#pragma unroll
        for (int i = 0; i < 4; ++i) {
            af[i] = *(const short8*)(smA + (wm + i * 16 + l15) * 32 + quad * 8);
            const int rb = wn + i * 16 + l15;
            bfr[i] = *(const short8*)(smB + rb * 32 + ((quad ^ ((rb >> 4) & 3)) * 8));
        }
#pragma unroll
        for (int mi = 0; mi < 4; ++mi)
#pragma unroll
            for (int ni = 0; ni < 4; ++ni)
                acc[mi][ni] = __builtin_amdgcn_mfma_f32_16x16x32_bf16(
                        af[mi], bfr[ni], acc[mi][ni], 0, 0, 0);
        __syncthreads();
    }

#pragma unroll
    for (int mi = 0; mi < 4; ++mi) {
        const int mb = wm + mi * 16 + quad * 4;
#pragma unroll
        for (int r = 0; r < 4; ++r) {
            const int m = mb + r;
#pragma unroll
            for (int ni = 0; ni < 4; ++ni) {
                const int nn = n0 + wn + ni * 16 + l15;
                Rb[(size_t)m * T_D + nn] = acc[mi][ni][r];
            }
        }
    }
}

extern "C" void kernel_launch(void* const* d_in, const int* in_sizes, int n_in,
                              void* d_out, int out_size, void* d_ws, size_t ws_size,
                              hipStream_t stream) {
    const float* Qf = (const float*)d_in[0];
    const float* Kf = (const float*)d_in[1];
    const float* Vf = (const float*)d_in[2];
    const float* Wq = (const float*)d_in[3];
    const float* bq = (const float*)d_in[4];
    const float* Wk = (const float*)d_in[5];
    const float* bk = (const float*)d_in[6];
    const float* Wv = (const float*)d_in[7];
    const float* bv = (const float*)d_in[8];

    float* Rout = (float*)d_out;
    float* Aout = Rout + (size_t)N_B * C_D * T_D;

    u16* QpT = (u16*)Rout;                 // bf16 (n,t,c) in R region
    u16* KpT = (u16*)Rout + 8388608;       // bf16 (n,s,c) in R region
    u16* Wqb = (u16*)Aout;                 // weights at head of A region (dead
    u16* Wkb = Wqb + 65536;                //   before scores writes A)
    u16* Wvb = Wkb + 65536;
    u16* Vp  = (u16*)d_in[0];              // bf16 (n,c,s) — Q consumed by then

    // softmax partials in d_in[1] (K fp32, dead after K projection): 2.4 MB
    float* Pm = (float*)d_in[1];
    float* Pl = Pm + (size_t)N_B * 8 * T_D;
    float* Mf = Pl + (size_t)N_B * 8 * T_D;
    float* Rl = Mf + (size_t)N_B * T_D;

    dim3 blk(256);
    const long sX = (long)C_D * T_D;
    const long sS = (long)T_D * T_D;

    // 1) weights fp32 -> bf16
    conv_w<<<dim3(256, 3), blk, 0, stream>>>(Wq, Wk, Wv, Wqb, Wkb, Wvb);

    // 2) projections, transpose+convert fused into staging
    gemm_t<true, false, 1, false><<<dim3(2, 8, N_B), blk, 0, stream>>>(
            Qf, Wqb, bq, QpT, C_D, C_D, sX, 0, sX, 1.0f, nullptr, nullptr);
    gemm_t<true, false, 1, false><<<dim3(2, 8, N_B), blk, 0, stream>>>(
            Kf, Wkb, bk, KpT, C_D, C_D, sX, 0, sX, 1.0f, nullptr, nullptr);
    gemm_t<false, true, 2, false><<<dim3(8, 2, N_B), blk, 0, stream>>>(
            Wvb, Vf, bv, Vp, C_D, T_D, 0, sX, sX, 1.0f, nullptr, nullptr);

    // 3) scores: S = Kp.Qp/16 -> raw fp32 into Aout + per-block (m,l) partials
    gemm_t<false, false, 3, true><<<dim3(8, 8, N_B), blk, 0, stream>>>(
            KpT, QpT, nullptr, Aout, C_D, T_D, sX, sX, sS, 0.0625f, Pm, Pl);

    // 4) merge partials -> global M[t], 1/L[t]
    merge_ml<<<dim3(128), blk, 0, stream>>>(Pm, Pl, Mf, Rl);

    // 5) fused: normalize S -> A in place + R = Vp . A
    gemm_rn<<<dim3(8, 1, N_B), dim3(512), 0, stream>>>(Vp, Aout, Mf, Rl, Rout);
}

// Round 5
// 381.270 us; speedup vs baseline: 1.9997x; 1.0222x over previous
//
#include <hip/hip_runtime.h>
#include <stdint.h>

#define N_B 32
#define C_D 256
#define T_D 1024

typedef unsigned short u16;
typedef __attribute__((ext_vector_type(8))) short short8;
typedef __attribute__((ext_vector_type(4))) float f32x4;

__device__ __forceinline__ u16 f2bf(float f) {
    unsigned x = __float_as_uint(f);
    return (u16)((x + 0x7fffu + ((x >> 16) & 1u)) >> 16);  // RNE
}

__device__ __forceinline__ void gld16(const void* g, void* l) {
    __builtin_amdgcn_global_load_lds(
        (const __attribute__((address_space(1))) uint32_t*)g,
        (__attribute__((address_space(3))) uint32_t*)l, 16, 0, 0);
}

// flash-style (m,l) merge
__device__ __forceinline__ void comb(float& m, float& l, float m2, float l2) {
    float M = fmaxf(m, m2);
    l = l * __expf(m - M) + l2 * __expf(m2 - M);
    m = M;
}

// ---- weights: 3x (256x256) fp32 -> bf16, one launch ----
__global__ __launch_bounds__(256) void conv_w(const float* __restrict__ w0,
                                              const float* __restrict__ w1,
                                              const float* __restrict__ w2,
                                              u16* __restrict__ o0,
                                              u16* __restrict__ o1,
                                              u16* __restrict__ o2) {
    const float* in = blockIdx.y == 0 ? w0 : (blockIdx.y == 1 ? w1 : w2);
    u16* out       = blockIdx.y == 0 ? o0 : (blockIdx.y == 1 ? o1 : o2);
    int i = blockIdx.x * 256 + threadIdx.x;
    out[i] = f2bf(in[i]);
}

// ---- staged transpose+convert: fp32 k-major source (row stride T_D) -> LDS
// [cols][32 k] bf16 tile, XOR-swizzled (chunk ^ ((t>>4)&3)<<3).
// Caller provides sr2 (k-pair index) and tt8 (col base).
// NORM: y = exp(x - Mv[col])*Rv[col]; if awr, write fp32 y back to adst
// (adst MAY alias src — loads precede stores).
template <bool NORM>
__device__ __forceinline__ void stage_tr(const float* src, u16* sm,
                                         int sr2, int tt8,
                                         const float* Mv, const float* Rv,
                                         float* adst, bool awr) {
    float4 v0 = *(const float4*)(src);
    float4 v1 = *(const float4*)(src + 4);
    float4 w0 = *(const float4*)(src + T_D);
    float4 w1 = *(const float4*)(src + T_D + 4);
    float a[8] = {v0.x, v0.y, v0.z, v0.w, v1.x, v1.y, v1.z, v1.w};
    float b[8] = {w0.x, w0.y, w0.z, w0.w, w1.x, w1.y, w1.z, w1.w};
    if constexpr (NORM) {
#pragma unroll
        for (int j = 0; j < 8; ++j) {
            a[j] = __expf(a[j] - Mv[j]) * Rv[j];
            b[j] = __expf(b[j] - Mv[j]) * Rv[j];
        }
        if (awr) {
            ((float4*)adst)[0]         = make_float4(a[0], a[1], a[2], a[3]);
            ((float4*)adst)[1]         = make_float4(a[4], a[5], a[6], a[7]);
            ((float4*)(adst + T_D))[0] = make_float4(b[0], b[1], b[2], b[3]);
            ((float4*)(adst + T_D))[1] = make_float4(b[4], b[5], b[6], b[7]);
        }
    }
    const int kk = sr2 * 2;
#pragma unroll
    for (int j = 0; j < 8; ++j) {
        const int t  = tt8 + j;
        const int ks = kk ^ (((t >> 4) & 3) << 3);
        uint32_t pk = (uint32_t)f2bf(a[j]) | ((uint32_t)f2bf(b[j]) << 16);
        *(uint32_t*)(sm + t * 32 + ks) = pk;
    }
}

// --------- unified GEMM: Out[m,n] = epi(scale * sum_k A[m,k]*B[n,k]) -------
// TRA/TRB: that side is fp32 k-major (row stride T_D), transposed+converted
// at staging. Otherwise bf16 rows K-contig (stride Kdim), gld16-staged with
// SOURCE-swizzled chunks (chunk ^ ((row>>1)&3)) so fragment ds_read_b128 is
// 2-way (free) instead of 8-way bank-conflicted.
// EPI: 0 = scale only; 1 = tanh(x + bias[n]); 2 = tanh(x + bias[m]);
//      3 = scale + store fp32 + per-column (max,sumexp) partials to Pm/Pl.
// DUAL: blockIdx.z in [N_B,2*N_B) uses the second operand set (Q+K merge).
template <bool TRA, bool TRB, int EPI, bool F32OUT, bool DUAL>
__global__ __launch_bounds__(256) void gemm_t(
        const void* __restrict__ Av, const void* __restrict__ Bv,
        const float* __restrict__ bias, void* __restrict__ OutV,
        int Kdim, int ldo, long sA, long sB, long sO, float scale,
        float* __restrict__ Pm, float* __restrict__ Pl,
        const void* __restrict__ Av2, const void* __restrict__ Bv2,
        const float* __restrict__ bias2, void* __restrict__ Out2)
{
    __shared__ __align__(16) u16 smA[128 * 32];
    __shared__ __align__(16) u16 smB[128 * 32];

    int nb = blockIdx.z;
    if (DUAL && nb >= N_B) {
        nb -= N_B;
        Av = Av2; Bv = Bv2; bias = bias2; OutV = Out2;
    }
    const int n0 = blockIdx.x * 128;
    const int m0 = blockIdx.y * 128;
    const int tid = threadIdx.x;

    const int srow = tid >> 2;
    const int sk8  = (((tid & 3) ^ ((srow >> 1) & 3)) * 8);  // src-swizzled
    const int sr2  = tid >> 4;
    const int tt8  = (tid & 15) * 8;

    const u16* gA0 = nullptr; const u16* gA1 = nullptr;
    const float* tA = nullptr;
    if constexpr (TRA) {
        tA = (const float*)Av + (size_t)nb * sA + (size_t)(sr2 * 2) * T_D + m0 + tt8;
    } else {
        const u16* Ab = (const u16*)Av + (size_t)nb * sA;
        gA0 = Ab + (size_t)(m0 + srow) * Kdim + sk8;
        gA1 = gA0 + (size_t)64 * Kdim;
    }
    const u16* gB0 = nullptr; const u16* gB1 = nullptr;
    const float* tB = nullptr;
    if constexpr (TRB) {
        tB = (const float*)Bv + (size_t)nb * sB + (size_t)(sr2 * 2) * T_D + n0 + tt8;
    } else {
        const u16* Bb = (const u16*)Bv + (size_t)nb * sB;
        gB0 = Bb + (size_t)(n0 + srow) * Kdim + sk8;
        gB1 = gB0 + (size_t)64 * Kdim;
    }
    u16* lA0 = smA + tid * 8; u16* lA1 = smA + 2048 + tid * 8;
    u16* lB0 = smB + tid * 8; u16* lB1 = smB + 2048 + tid * 8;

    const int lane = tid & 63;
    const int w    = tid >> 6;
    const int wm   = (w >> 1) * 64;
    const int wn   = (w & 1) * 64;
    const int l15  = lane & 15;
    const int quad = lane >> 4;

    f32x4 acc[4][4];
#pragma unroll
    for (int i = 0; i < 4; ++i)
#pragma unroll
        for (int j = 0; j < 4; ++j) acc[i][j] = (f32x4){0.f, 0.f, 0.f, 0.f};

    for (int kb = 0; kb < Kdim; kb += 32) {
        if constexpr (TRA) {
            stage_tr<false>(tA + (size_t)kb * T_D, smA, sr2, tt8,
                            nullptr, nullptr, nullptr, false);
        } else {
            gld16(gA0 + kb, lA0);
            gld16(gA1 + kb, lA1);
        }
        if constexpr (TRB) {
            stage_tr<false>(tB + (size_t)kb * T_D, smB, sr2, tt8,
                            nullptr, nullptr, nullptr, false);
        } else {
            gld16(gB0 + kb, lB0);
            gld16(gB1 + kb, lB1);
        }
        __syncthreads();
        short8 af[4], bfr[4];
#pragma unroll
        for (int i = 0; i < 4; ++i) {
            const int ra = wm + i * 16 + l15;
            const int ca = TRA ? ((quad ^ ((ra >> 4) & 3)) * 8)
                               : ((quad ^ ((ra >> 1) & 3)) * 8);
            af[i] = *(const short8*)(smA + ra * 32 + ca);
            const int rb = wn + i * 16 + l15;
            const int cb = TRB ? ((quad ^ ((rb >> 4) & 3)) * 8)
                               : ((quad ^ ((rb >> 1) & 3)) * 8);
            bfr[i] = *(const short8*)(smB + rb * 32 + cb);
        }
#pragma unroll
        for (int mi = 0; mi < 4; ++mi)
#pragma unroll
            for (int ni = 0; ni < 4; ++ni)
                acc[mi][ni] = __builtin_amdgcn_mfma_f32_16x16x32_bf16(
                        af[mi], bfr[ni], acc[mi][ni], 0, 0, 0);
        __syncthreads();
    }

    if constexpr (EPI == 3) {
        float pmv[4] = {-1e30f, -1e30f, -1e30f, -1e30f};
        float plv[4] = {0.f, 0.f, 0.f, 0.f};
#pragma unroll
        for (int mi = 0; mi < 4; ++mi) {
            const int mb = m0 + wm + mi * 16 + quad * 4;
#pragma unroll
            for (int r = 0; r < 4; ++r) {
                const int m = mb + r;
#pragma unroll
                for (int ni = 0; ni < 4; ++ni) {
                    const int nn = n0 + wn + ni * 16 + l15;
                    float v = acc[mi][ni][r] * scale;
                    ((float*)OutV)[(size_t)nb * sO + (size_t)m * ldo + nn] = v;
                    pmv[ni] = fmaxf(pmv[ni], v);
                }
            }
        }
#pragma unroll
        for (int ni = 0; ni < 4; ++ni) {
            float s = 0.f;
#pragma unroll
            for (int mi = 0; mi < 4; ++mi)
#pragma unroll
                for (int r = 0; r < 4; ++r)
                    s += __expf(acc[mi][ni][r] * scale - pmv[ni]);
            plv[ni] = s;
        }
#pragma unroll
        for (int ni = 0; ni < 4; ++ni) {
            float m = pmv[ni], l = plv[ni];
            float m2 = __shfl_xor(m, 16), l2 = __shfl_xor(l, 16);
            comb(m, l, m2, l2);
            m2 = __shfl_xor(m, 32); l2 = __shfl_xor(l, 32);
            comb(m, l, m2, l2);
            pmv[ni] = m; plv[ni] = l;
        }
        __shared__ float red_m[4][64];
        __shared__ float red_l[4][64];
        if (quad == 0) {
#pragma unroll
            for (int ni = 0; ni < 4; ++ni) {
                red_m[w][ni * 16 + l15] = pmv[ni];
                red_l[w][ni * 16 + l15] = plv[ni];
            }
        }
        __syncthreads();
        if (tid < 128) {
            const int half = tid >> 6, cc = tid & 63;
            float m = red_m[half][cc], l = red_l[half][cc];
            comb(m, l, red_m[half + 2][cc], red_l[half + 2][cc]);
            const size_t pi = ((size_t)nb * 8 + blockIdx.y) * T_D + n0 + tid;
            Pm[pi] = m; Pl[pi] = l;
        }
    } else {
#pragma unroll
        for (int mi = 0; mi < 4; ++mi) {
            const int mb = m0 + wm + mi * 16 + quad * 4;
#pragma unroll
            for (int r = 0; r < 4; ++r) {
                const int m = mb + r;
                float bm = 0.f;
                if (EPI == 2) bm = bias[m];
#pragma unroll
                for (int ni = 0; ni < 4; ++ni) {
                    const int nn = n0 + wn + ni * 16 + l15;
                    float v = acc[mi][ni][r] * scale;
                    if (EPI == 1) v = tanhf(v + bias[nn]);
                    if (EPI == 2) v = tanhf(v + bm);
                    if (F32OUT)
                        ((float*)OutV)[(size_t)nb * sO + (size_t)m * ldo + nn] = v;
                    else
                        ((u16*)OutV)[(size_t)nb * sO + (size_t)m * ldo + nn] = f2bf(v);
                }
            }
        }
    }
}

// ---- merge per-s-tile partials: M = max, Rl = 1/sum(l*exp(m-M)) ----
__global__ __launch_bounds__(256) void merge_ml(const float* __restrict__ Pm,
                                                const float* __restrict__ Pl,
                                                float* __restrict__ Mf,
                                                float* __restrict__ Rl) {
    const int i = blockIdx.x * 256 + threadIdx.x;  // over N_B*T_D
    const int n = i >> 10, t = i & (T_D - 1);
    const float* pm = Pm + (size_t)n * 8 * T_D + t;
    const float* pl = Pl + (size_t)n * 8 * T_D + t;
    float M = -1e30f;
#pragma unroll
    for (int j = 0; j < 8; ++j) M = fmaxf(M, pm[(size_t)j * T_D]);
    float L = 0.f;
#pragma unroll
    for (int j = 0; j < 8; ++j) L += pl[(size_t)j * T_D] * __expf(pm[(size_t)j * T_D] - M);
    Mf[i] = M;
    Rl[i] = 1.0f / L;
}

// ----- fused R GEMM: R(c,t) = sum_s Vp(c,s) * A(s,t), A = exp(S-M)*rL -----
// BM=256 (all c), BN=64; 512 threads / 8 waves; grid (16,1,N_B) = 2 blk/CU.
// Each block exclusively owns its (nb, 64-col t-panel) of S: staging reads
// raw S, normalizes, writes fp32 A back IN PLACE, feeds bf16 frags to MFMA.
__global__ __launch_bounds__(512) void gemm_rn(
        const u16* __restrict__ Vp, float* S,
        const float* __restrict__ Mf, const float* __restrict__ Rl,
        float* __restrict__ R)
{
    __shared__ __align__(16) u16 smA[256 * 32];   // 16 KB
    __shared__ __align__(16) u16 smB[64 * 32];    // 4 KB

    const int nb  = blockIdx.z;
    const int n0  = blockIdx.x * 64;
    const int tid = threadIdx.x;

    const u16* Ab = Vp + (size_t)nb * (C_D * T_D);
    float* Sb = S + (size_t)nb * ((size_t)T_D * T_D);
    float* Rb = R + (size_t)nb * (C_D * T_D);

    const int srow = tid >> 2;        // 0..127
    const int sk8  = (((tid & 3) ^ ((srow >> 1) & 3)) * 8);  // src-swizzled
    const u16* gA0 = Ab + (size_t)srow * T_D + sk8;
    const u16* gA1 = gA0 + (size_t)128 * T_D;
    u16* lA0 = smA + tid * 8;
    u16* lA1 = smA + 4096 + tid * 8;

    float Mv[8], Rv[8];
    float* tB = nullptr;
    int bsr2 = 0, btt8 = 0;
    if (tid < 128) {
        bsr2 = tid >> 3;              // k-pair 0..15
        btt8 = (tid & 7) * 8;         // col base 0..56
        tB = Sb + (size_t)(bsr2 * 2) * T_D + n0 + btt8;
#pragma unroll
        for (int j = 0; j < 8; ++j) {
            Mv[j] = Mf[(size_t)nb * T_D + n0 + btt8 + j];
            Rv[j] = Rl[(size_t)nb * T_D + n0 + btt8 + j];
        }
    }

    const int lane = tid & 63;
    const int w    = tid >> 6;        // 0..7
    const int wm   = (w >> 1) * 64;   // 0,64,128,192 (c)
    const int wn   = (w & 1) * 32;    // 0,32 (t)
    const int l15  = lane & 15;
    const int quad = lane >> 4;

    f32x4 acc[4][2];
#pragma unroll
    for (int i = 0; i < 4; ++i)
#pragma unroll
        for (int j = 0; j < 2; ++j) acc[i][j] = (f32x4){0.f, 0.f, 0.f, 0.f};

    for (int kb = 0; kb < T_D; kb += 32) {
        gld16(gA0 + kb, lA0);
        gld16(gA1 + kb, lA1);
        if (tid < 128) {
            float* src = tB + (size_t)kb * T_D;
            stage_tr<true>(src, smB, bsr2, btt8, Mv, Rv, src, true);
        }
        __syncthreads();
        short8 af[4], bfr[2];
#pragma unroll
        for (int i = 0; i < 4; ++i) {
            const int ra = wm + i * 16 + l15;
            af[i] = *(const short8*)(smA + ra * 32 + ((quad ^ ((ra >> 1) & 3)) * 8));
        }
#pragma unroll
        for (int i = 0; i < 2; ++i) {
            const int rb = wn + i * 16 + l15;
            bfr[i] = *(const short8*)(smB + rb * 32 + ((quad ^ ((rb >> 4) & 3)) * 8));
        }
#pragma unroll
        for (int mi = 0; mi < 4; ++mi)
#pragma unroll
            for (int ni = 0; ni < 2; ++ni)
                acc[mi][ni] = __builtin_amdgcn_mfma_f32_16x16x32_bf16(
                        af[mi], bfr[ni], acc[mi][ni], 0, 0, 0);
        __syncthreads();
    }

#pragma unroll
    for (int mi = 0; mi < 4; ++mi) {
        const int mb = wm + mi * 16 + quad * 4;
#pragma unroll
        for (int r = 0; r < 4; ++r) {
            const int m = mb + r;
#pragma unroll
            for (int ni = 0; ni < 2; ++ni) {
                const int nn = n0 + wn + ni * 16 + l15;
                Rb[(size_t)m * T_D + nn] = acc[mi][ni][r];
            }
        }
    }
}

extern "C" void kernel_launch(void* const* d_in, const int* in_sizes, int n_in,
                              void* d_out, int out_size, void* d_ws, size_t ws_size,
                              hipStream_t stream) {
    const float* Qf = (const float*)d_in[0];
    const float* Kf = (const float*)d_in[1];
    const float* Vf = (const float*)d_in[2];
    const float* Wq = (const float*)d_in[3];
    const float* bq = (const float*)d_in[4];
    const float* Wk = (const float*)d_in[5];
    const float* bk = (const float*)d_in[6];
    const float* Wv = (const float*)d_in[7];
    const float* bv = (const float*)d_in[8];

    float* Rout = (float*)d_out;
    float* Aout = Rout + (size_t)N_B * C_D * T_D;

    u16* QpT = (u16*)Rout;                 // bf16 (n,t,c) in R region
    u16* KpT = (u16*)Rout + 8388608;       // bf16 (n,s,c) in R region
    u16* Wqb = (u16*)Aout;                 // weights at head of A region (dead
    u16* Wkb = Wqb + 65536;                //   before scores writes A)
    u16* Wvb = Wkb + 65536;
    u16* Vp  = (u16*)d_in[0];              // bf16 (n,c,s) — Q consumed by then

    // softmax partials in d_in[1] (K fp32, dead after K projection): 2.4 MB
    float* Pm = (float*)d_in[1];
    float* Pl = Pm + (size_t)N_B * 8 * T_D;
    float* Mf = Pl + (size_t)N_B * 8 * T_D;
    float* Rl = Mf + (size_t)N_B * T_D;

    dim3 blk(256);
    const long sX = (long)C_D * T_D;
    const long sS = (long)T_D * T_D;

    // 1) weights fp32 -> bf16
    conv_w<<<dim3(256, 3), blk, 0, stream>>>(Wq, Wk, Wv, Wqb, Wkb, Wvb);

    // 2) Q+K projections in ONE launch (z in [0,32) = Q, [32,64) = K)
    gemm_t<true, false, 1, false, true><<<dim3(2, 8, 2 * N_B), blk, 0, stream>>>(
            Qf, Wqb, bq, QpT, C_D, C_D, sX, 0, sX, 1.0f, nullptr, nullptr,
            Kf, Wkb, bk, KpT);
    //    V projection
    gemm_t<false, true, 2, false, false><<<dim3(8, 2, N_B), blk, 0, stream>>>(
            Wvb, Vf, bv, Vp, C_D, T_D, 0, sX, sX, 1.0f, nullptr, nullptr,
            nullptr, nullptr, nullptr, nullptr);

    // 3) scores: S = Kp.Qp/16 -> raw fp32 into Aout + per-block (m,l) partials
    gemm_t<false, false, 3, true, false><<<dim3(8, 8, N_B), blk, 0, stream>>>(
            KpT, QpT, nullptr, Aout, C_D, T_D, sX, sX, sS, 0.0625f, Pm, Pl,
            nullptr, nullptr, nullptr, nullptr);

    // 4) merge partials -> global M[t], 1/L[t]
    merge_ml<<<dim3(128), blk, 0, stream>>>(Pm, Pl, Mf, Rl);

    // 5) fused: normalize S -> A in place + R = Vp . A
    gemm_rn<<<dim3(16, 1, N_B), dim3(512), 0, stream>>>(Vp, Aout, Mf, Rl, Rout);
}

// Round 7
// 369.280 us; speedup vs baseline: 2.0646x; 1.0325x over previous
//
#include <hip/hip_runtime.h>
#include <stdint.h>

#define N_B 32
#define C_D 256
#define T_D 1024
#define QB 32

typedef unsigned short u16;
typedef __attribute__((ext_vector_type(8))) short short8;
typedef __attribute__((ext_vector_type(4))) float f32x4;

__device__ __forceinline__ u16 f2bf(float f) {
    unsigned x = __float_as_uint(f);
    return (u16)((x + 0x7fffu + ((x >> 16) & 1u)) >> 16);  // RNE
}

__device__ __forceinline__ void gld16(const void* g, void* l) {
    __builtin_amdgcn_global_load_lds(
        (const __attribute__((address_space(1))) uint32_t*)g,
        (__attribute__((address_space(3))) uint32_t*)l, 16, 0, 0);
}

// flash-style (m,l) merge
__device__ __forceinline__ void comb(float& m, float& l, float m2, float l2) {
    float M = fmaxf(m, m2);
    l = l * __expf(m - M) + l2 * __expf(m2 - M);
    m = M;
}

// ---- weights: 3x (256x256) fp32 -> bf16, one launch ----
__global__ __launch_bounds__(256) void conv_w(const float* __restrict__ w0,
                                              const float* __restrict__ w1,
                                              const float* __restrict__ w2,
                                              u16* __restrict__ o0,
                                              u16* __restrict__ o1,
                                              u16* __restrict__ o2) {
    const float* in = blockIdx.y == 0 ? w0 : (blockIdx.y == 1 ? w1 : w2);
    u16* out       = blockIdx.y == 0 ? o0 : (blockIdx.y == 1 ? o1 : o2);
    int i = blockIdx.x * 256 + threadIdx.x;
    out[i] = f2bf(in[i]);
}

// ---- staged transpose+convert: fp32 k-major source (row stride T_D) -> LDS
// [cols][32 k] bf16 tile, XOR-swizzled (chunk ^ ((t>>4)&3)<<3).
__device__ __forceinline__ void stage_tr(const float* __restrict__ src,
                                         u16* __restrict__ sm,
                                         int sr2, int tt8) {
    float4 v0 = *(const float4*)(src);
    float4 v1 = *(const float4*)(src + 4);
    float4 w0 = *(const float4*)(src + T_D);
    float4 w1 = *(const float4*)(src + T_D + 4);
    float a[8] = {v0.x, v0.y, v0.z, v0.w, v1.x, v1.y, v1.z, v1.w};
    float b[8] = {w0.x, w0.y, w0.z, w0.w, w1.x, w1.y, w1.z, w1.w};
    const int kk = sr2 * 2;
#pragma unroll
    for (int j = 0; j < 8; ++j) {
        const int t  = tt8 + j;
        const int ks = kk ^ (((t >> 4) & 3) << 3);
        uint32_t pk = (uint32_t)f2bf(a[j]) | ((uint32_t)f2bf(b[j]) << 16);
        *(uint32_t*)(sm + t * 32 + ks) = pk;
    }
}

// --------- unified GEMM: Out[m,n] = epi(scale * sum_k A[m,k]*B[n,k]) -------
// TRA/TRB: that side is fp32 k-major (row stride T_D), transposed+converted
// at staging. Otherwise bf16 rows K-contig (stride Kdim), gld16-staged with
// SOURCE-swizzled chunks so fragment ds_read_b128 is 2-way (free).
// EPI: 1 = tanh(x + bias[n]); 2 = tanh(x + bias[m])
// DUAL: blockIdx.z in [N_B,2*N_B) uses the second operand set (Q+K merge).
template <bool TRA, bool TRB, int EPI, bool DUAL>
__global__ __launch_bounds__(256) void gemm_t(
        const void* __restrict__ Av, const void* __restrict__ Bv,
        const float* __restrict__ bias, void* __restrict__ OutV,
        int Kdim, int ldo, long sA, long sB, long sO, float scale,
        const void* __restrict__ Av2, const void* __restrict__ Bv2,
        const float* __restrict__ bias2, void* __restrict__ Out2)
{
    __shared__ __align__(16) u16 smA[128 * 32];
    __shared__ __align__(16) u16 smB[128 * 32];

    int nb = blockIdx.z;
    if (DUAL && nb >= N_B) {
        nb -= N_B;
        Av = Av2; Bv = Bv2; bias = bias2; OutV = Out2;
    }
    const int n0 = blockIdx.x * 128;
    const int m0 = blockIdx.y * 128;
    const int tid = threadIdx.x;

    const int srow = tid >> 2;
    const int sk8  = (((tid & 3) ^ ((srow >> 1) & 3)) * 8);  // src-swizzled
    const int sr2  = tid >> 4;
    const int tt8  = (tid & 15) * 8;

    const u16* gA0 = nullptr; const u16* gA1 = nullptr;
    const float* tA = nullptr;
    if constexpr (TRA) {
        tA = (const float*)Av + (size_t)nb * sA + (size_t)(sr2 * 2) * T_D + m0 + tt8;
    } else {
        const u16* Ab = (const u16*)Av + (size_t)nb * sA;
        gA0 = Ab + (size_t)(m0 + srow) * Kdim + sk8;
        gA1 = gA0 + (size_t)64 * Kdim;
    }
    const u16* gB0 = nullptr; const u16* gB1 = nullptr;
    const float* tB = nullptr;
    if constexpr (TRB) {
        tB = (const float*)Bv + (size_t)nb * sB + (size_t)(sr2 * 2) * T_D + n0 + tt8;
    } else {
        const u16* Bb = (const u16*)Bv + (size_t)nb * sB;
        gB0 = Bb + (size_t)(n0 + srow) * Kdim + sk8;
        gB1 = gB0 + (size_t)64 * Kdim;
    }
    u16* lA0 = smA + tid * 8; u16* lA1 = smA + 2048 + tid * 8;
    u16* lB0 = smB + tid * 8; u16* lB1 = smB + 2048 + tid * 8;

    const int lane = tid & 63;
    const int w    = tid >> 6;
    const int wm   = (w >> 1) * 64;
    const int wn   = (w & 1) * 64;
    const int l15  = lane & 15;
    const int quad = lane >> 4;

    f32x4 acc[4][4];
#pragma unroll
    for (int i = 0; i < 4; ++i)
#pragma unroll
        for (int j = 0; j < 4; ++j) acc[i][j] = (f32x4){0.f, 0.f, 0.f, 0.f};

    for (int kb = 0; kb < Kdim; kb += 32) {
        if constexpr (TRA) {
            stage_tr(tA + (size_t)kb * T_D, smA, sr2, tt8);
        } else {
            gld16(gA0 + kb, lA0);
            gld16(gA1 + kb, lA1);
        }
        if constexpr (TRB) {
            stage_tr(tB + (size_t)kb * T_D, smB, sr2, tt8);
        } else {
            gld16(gB0 + kb, lB0);
            gld16(gB1 + kb, lB1);
        }
        __syncthreads();
        short8 af[4], bfr[4];
#pragma unroll
        for (int i = 0; i < 4; ++i) {
            const int ra = wm + i * 16 + l15;
            const int ca = TRA ? ((quad ^ ((ra >> 4) & 3)) * 8)
                               : ((quad ^ ((ra >> 1) & 3)) * 8);
            af[i] = *(const short8*)(smA + ra * 32 + ca);
            const int rb = wn + i * 16 + l15;
            const int cb = TRB ? ((quad ^ ((rb >> 4) & 3)) * 8)
                               : ((quad ^ ((rb >> 1) & 3)) * 8);
            bfr[i] = *(const short8*)(smB + rb * 32 + cb);
        }
#pragma unroll
        for (int mi = 0; mi < 4; ++mi)
#pragma unroll
            for (int ni = 0; ni < 4; ++ni)
                acc[mi][ni] = __builtin_amdgcn_mfma_f32_16x16x32_bf16(
                        af[mi], bfr[ni], acc[mi][ni], 0, 0, 0);
        __syncthreads();
    }

#pragma unroll
    for (int mi = 0; mi < 4; ++mi) {
        const int mb = m0 + wm + mi * 16 + quad * 4;
#pragma unroll
        for (int r = 0; r < 4; ++r) {
            const int m = mb + r;
            float bm = 0.f;
            if (EPI == 2) bm = bias[m];
#pragma unroll
            for (int ni = 0; ni < 4; ++ni) {
                const int nn = n0 + wn + ni * 16 + l15;
                float v = acc[mi][ni][r] * scale;
                if (EPI == 1) v = tanhf(v + bias[nn]);
                if (EPI == 2) v = tanhf(v + bm);
                ((u16*)OutV)[(size_t)nb * sO + (size_t)m * ldo + nn] = f2bf(v);
            }
        }
    }
}

// ===================== fused scores+softmax+PV kernel =====================
// One block per (nb, 32-wide t-panel). 512 thr / 8 waves, 80 KB LDS.
// Phase 1: S(s=0..1023, t-panel) = Kp.Qp^T / 16 into registers (acc[8][2]).
// Softmax over s fully on-chip (quad shfl + 8-wave LDS merge) -> M[t], 1/L[t].
// Normalize writes fp32 A (only HBM trip for S) + packs bf16 P into LDS.
// Phase 2: R(c,t) = Vp . P. Wave-private staging -> no barrier in K-loops.
// NOTE: `red` aliases smQ — it is written ONLY after the post-phase-1
// __syncthreads(), when no wave can still be reading Q (round-6 race fix).
__global__ __launch_bounds__(512, 4) void attn_fused(
        const u16* __restrict__ Kp,   // (n,s,c) bf16
        const u16* __restrict__ Qp,   // (n,t,c) bf16
        const u16* __restrict__ Vp,   // (n,c,s) bf16
        float* __restrict__ A,        // (n,s,t) fp32 out
        float* __restrict__ Rr)       // (n,c,t) fp32 out (scratch home)
{
    __shared__ __align__(16) u16 lds[40960];   // 80 KB
    u16* smK = lds;                  // p1: [1024 s][4 slot(8c)]  64 KB (wave-priv)
    u16* smQ = lds + 32768;          // p1: [32 t][32 slot(8c)]   16 KB (shared)
    u16* smP = lds;                  // p2: [32 t][128 slot8(8s)] 64 KB (shared)
    u16* smV = lds + 32768;          // p2: [256 c][4 slot(8s)]   16 KB (wave-priv)
    float* red = (float*)(lds + 32768);  // softmax scratch (smQ dead by then)

    const int bid = blockIdx.x;
    const int idx = (bid & 7) * 128 + (bid >> 3);   // XCD-contiguous remap
    const int nb  = idx >> 5;
    const int t0  = (idx & 31) * QB;

    const int tid  = threadIdx.x;
    const int lane = tid & 63;
    const int w    = tid >> 6;
    const int l15  = lane & 15;
    const int quad = lane >> 4;

    const u16* Kb = Kp + (size_t)nb * (T_D * C_D);
    const u16* Qb = Qp + (size_t)nb * (T_D * C_D);
    const u16* Vb = Vp + (size_t)nb * (C_D * T_D);
    float* Ab = A + (size_t)nb * ((size_t)T_D * T_D) + t0;
    float* Rb = Rr + (size_t)nb * (C_D * T_D) + t0;

    // ---- stage Qp panel (block-shared, source-swizzled) ----
    {
        const int tq   = tid >> 5;      // 0..15
        const int slot = tid & 31;
#pragma unroll
        for (int c = 0; c < 2; ++c) {
            const int tt = c * 16 + tq;
            const int chunk = slot ^ (tt & 7);
            gld16(Qb + (size_t)(t0 + tt) * C_D + chunk * 8,
                  smQ + c * 4096 + tid * 8);
        }
    }

    f32x4 acc[8][2];
#pragma unroll
    for (int i = 0; i < 8; ++i)
#pragma unroll
        for (int j = 0; j < 2; ++j) acc[i][j] = (f32x4){0.f, 0.f, 0.f, 0.f};

    __syncthreads();   // smQ ready (vmcnt drained at barrier)

    // ---- phase 1: wave w owns s-rows [w*128,(w+1)*128), barrier-free ----
    u16* smKw = smK + w * 4096;                       // 8 KB wave region
    const u16* Kw = Kb + (size_t)(w * 128) * C_D;
    for (int kb = 0; kb < 8; ++kb) {
        asm volatile("s_waitcnt lgkmcnt(0)" ::: "memory");  // prev reads done
#pragma unroll
        for (int c = 0; c < 8; ++c) {
            const int s  = c * 16 + (lane >> 2);            // wave-local row
            const int ck = (lane & 3) ^ ((s >> 1) & 3);
            gld16(Kw + (size_t)s * C_D + kb * 32 + ck * 8,
                  smKw + c * 512 + lane * 8);
        }
        asm volatile("s_waitcnt vmcnt(0)" ::: "memory");
        __builtin_amdgcn_sched_barrier(0);
        short8 af[8], bq[2];
#pragma unroll
        for (int i = 0; i < 8; ++i) {
            const int sl = i * 16 + l15;
            af[i] = *(const short8*)(smKw + sl * 32 + ((quad ^ ((sl >> 1) & 3)) * 8));
        }
#pragma unroll
        for (int i = 0; i < 2; ++i) {
            const int t = i * 16 + l15;
            bq[i] = *(const short8*)(smQ + t * 256 + (((kb * 4 + quad) ^ (l15 & 7)) * 8));
        }
#pragma unroll
        for (int mi = 0; mi < 8; ++mi)
#pragma unroll
            for (int ni = 0; ni < 2; ++ni)
                acc[mi][ni] = __builtin_amdgcn_mfma_f32_16x16x32_bf16(
                        af[mi], bq[ni], acc[mi][ni], 0, 0, 0);
    }

    // ---- softmax over s: per-thread -> quad shfl -> 8-wave LDS merge ----
    float pm2[2], pl2[2];
#pragma unroll
    for (int ni = 0; ni < 2; ++ni) {
        float m = -1e30f;
#pragma unroll
        for (int mi = 0; mi < 8; ++mi)
#pragma unroll
            for (int r = 0; r < 4; ++r)
                m = fmaxf(m, acc[mi][ni][r] * 0.0625f);
        float l = 0.f;
#pragma unroll
        for (int mi = 0; mi < 8; ++mi)
#pragma unroll
            for (int r = 0; r < 4; ++r)
                l += __expf(acc[mi][ni][r] * 0.0625f - m);
        float m2 = __shfl_xor(m, 16), l2 = __shfl_xor(l, 16);
        comb(m, l, m2, l2);
        m2 = __shfl_xor(m, 32); l2 = __shfl_xor(l, 32);
        comb(m, l, m2, l2);
        pm2[ni] = m; pl2[ni] = l;
    }

    __syncthreads();   // ALL waves done with phase 1 (smQ/smK reads) —
                       // only now is `red` (aliasing smQ) safe to write.

    float* pmL = red;            // [8][32]
    float* plL = red + 256;
    float* fM  = red + 512;      // [32]
    float* fR  = red + 544;
    if (quad == 0) {
#pragma unroll
        for (int ni = 0; ni < 2; ++ni) {
            pmL[w * 32 + ni * 16 + l15] = pm2[ni];
            plL[w * 32 + ni * 16 + l15] = pl2[ni];
        }
    }
    __syncthreads();
    if (tid < 32) {
        float M = -1e30f;
#pragma unroll
        for (int j = 0; j < 8; ++j) M = fmaxf(M, pmL[j * 32 + tid]);
        float L = 0.f;
#pragma unroll
        for (int j = 0; j < 8; ++j)
            L += plL[j * 32 + tid] * __expf(pmL[j * 32 + tid] - M);
        fM[tid] = M;
        fR[tid] = 1.0f / L;
    }
    __syncthreads();
    float Mn[2], Rn[2];
#pragma unroll
    for (int ni = 0; ni < 2; ++ni) {
        Mn[ni] = fM[ni * 16 + l15];
        Rn[ni] = fR[ni * 16 + l15];
    }

    // ---- normalize: write fp32 A + pack bf16 P into LDS (swizzled) ----
#pragma unroll
    for (int mi = 0; mi < 8; ++mi) {
        const int sbase = w * 128 + mi * 16 + quad * 4;
        const int c4    = w * 32 + mi * 4 + quad;    // s-quartet index
        const int slot8 = c4 >> 1;
        const int half  = c4 & 1;
#pragma unroll
        for (int ni = 0; ni < 2; ++ni) {
            const int t = ni * 16 + l15;
            float a0 = __expf(acc[mi][ni][0] * 0.0625f - Mn[ni]) * Rn[ni];
            float a1 = __expf(acc[mi][ni][1] * 0.0625f - Mn[ni]) * Rn[ni];
            float a2 = __expf(acc[mi][ni][2] * 0.0625f - Mn[ni]) * Rn[ni];
            float a3 = __expf(acc[mi][ni][3] * 0.0625f - Mn[ni]) * Rn[ni];
            Ab[(size_t)(sbase + 0) * T_D + t] = a0;
            Ab[(size_t)(sbase + 1) * T_D + t] = a1;
            Ab[(size_t)(sbase + 2) * T_D + t] = a2;
            Ab[(size_t)(sbase + 3) * T_D + t] = a3;
            uint2 pk;
            pk.x = (uint32_t)f2bf(a0) | ((uint32_t)f2bf(a1) << 16);
            pk.y = (uint32_t)f2bf(a2) | ((uint32_t)f2bf(a3) << 16);
            *(uint2*)(smP + t * 1024 + (slot8 ^ (t & 7)) * 8 + half * 4) = pk;
        }
    }
    __syncthreads();   // P complete; fM/fR consumed; smV region free

    // ---- phase 2: R = Vp . P; wave w owns c-rows [w*32,(w+1)*32) ----
    f32x4 acc2[2][2];
#pragma unroll
    for (int i = 0; i < 2; ++i)
#pragma unroll
        for (int j = 0; j < 2; ++j) acc2[i][j] = (f32x4){0.f, 0.f, 0.f, 0.f};

    u16* smVw = smV + w * 1024;                     // 2 KB wave region
    for (int kb = 0; kb < 32; ++kb) {
        asm volatile("s_waitcnt lgkmcnt(0)" ::: "memory");
#pragma unroll
        for (int c = 0; c < 2; ++c) {
            const int cc = w * 32 + c * 16 + (lane >> 2);
            const int ck = (lane & 3) ^ ((cc >> 1) & 3);
            gld16(Vb + (size_t)cc * T_D + kb * 32 + ck * 8,
                  smVw + c * 512 + lane * 8);
        }
        asm volatile("s_waitcnt vmcnt(0)" ::: "memory");
        __builtin_amdgcn_sched_barrier(0);
        short8 av[2], pb[2];
#pragma unroll
        for (int i = 0; i < 2; ++i) {
            const int cc = w * 32 + i * 16 + l15;
            av[i] = *(const short8*)(smV + cc * 32 + ((quad ^ ((cc >> 1) & 3)) * 8));
            const int t = i * 16 + l15;
            pb[i] = *(const short8*)(smP + t * 1024 + (((kb * 4 + quad) ^ (l15 & 7)) * 8));
        }
#pragma unroll
        for (int mi = 0; mi < 2; ++mi)
#pragma unroll
            for (int ni = 0; ni < 2; ++ni)
                acc2[mi][ni] = __builtin_amdgcn_mfma_f32_16x16x32_bf16(
                        av[mi], pb[ni], acc2[mi][ni], 0, 0, 0);
    }

#pragma unroll
    for (int mi = 0; mi < 2; ++mi) {
        const int cb = w * 32 + mi * 16 + quad * 4;
#pragma unroll
        for (int r = 0; r < 4; ++r)
#pragma unroll
            for (int ni = 0; ni < 2; ++ni)
                Rb[(size_t)(cb + r) * T_D + ni * 16 + l15] = acc2[mi][ni][r];
    }
}

// ---- final R copy: d_in[1] scratch -> real output location ----
__global__ __launch_bounds__(256) void cp_r(const float4* __restrict__ s,
                                            float4* __restrict__ d) {
    const int n = N_B * C_D * T_D / 4;
    int i = blockIdx.x * 256 + threadIdx.x;
    const int st = gridDim.x * 256;
    for (; i < n; i += st) d[i] = s[i];
}

extern "C" void kernel_launch(void* const* d_in, const int* in_sizes, int n_in,
                              void* d_out, int out_size, void* d_ws, size_t ws_size,
                              hipStream_t stream) {
    const float* Qf = (const float*)d_in[0];
    const float* Kf = (const float*)d_in[1];
    const float* Vf = (const float*)d_in[2];
    const float* Wq = (const float*)d_in[3];
    const float* bq = (const float*)d_in[4];
    const float* Wk = (const float*)d_in[5];
    const float* bk = (const float*)d_in[6];
    const float* Wv = (const float*)d_in[7];
    const float* bv = (const float*)d_in[8];

    float* Rout = (float*)d_out;
    float* Aout = Rout + (size_t)N_B * C_D * T_D;

    u16* QpT = (u16*)Rout;                 // bf16 (n,t,c) in R region
    u16* KpT = (u16*)Rout + 8388608;       // bf16 (n,s,c) in R region
    u16* Wqb = (u16*)Aout;                 // weights at head of A region (dead
    u16* Wkb = Wqb + 65536;                //   before attn_fused writes A)
    u16* Wvb = Wkb + 65536;
    u16* Vp  = (u16*)d_in[0];              // bf16 (n,c,s) — Q consumed by then
    float* Rscr = (float*)d_in[1];         // R scratch — K consumed by then

    dim3 blk(256);
    const long sX = (long)C_D * T_D;

    // 1) weights fp32 -> bf16
    conv_w<<<dim3(256, 3), blk, 0, stream>>>(Wq, Wk, Wv, Wqb, Wkb, Wvb);

    // 2) Q+K projections in ONE launch (z in [0,32) = Q, [32,64) = K)
    gemm_t<true, false, 1, true><<<dim3(2, 8, 2 * N_B), blk, 0, stream>>>(
            Qf, Wqb, bq, QpT, C_D, C_D, sX, 0, sX, 1.0f,
            Kf, Wkb, bk, KpT);
    //    V projection
    gemm_t<false, true, 2, false><<<dim3(8, 2, N_B), blk, 0, stream>>>(
            Wvb, Vf, bv, Vp, C_D, T_D, 0, sX, sX, 1.0f,
            nullptr, nullptr, nullptr, nullptr);

    // 3) fused scores + exact softmax + A write + R = Vp.A
    attn_fused<<<dim3(1024), dim3(512), 0, stream>>>(KpT, QpT, Vp, Aout, Rscr);

    // 4) move R into place (QpT/KpT dead)
    cp_r<<<dim3(2048), blk, 0, stream>>>((const float4*)Rscr, (float4*)Rout);
}